// Round 4
// baseline (409.590 us; speedup 1.0000x reference)
//
#include <hip/hip_runtime.h>
#include <hip/hip_bf16.h>

#define TOKENS  2048
#define IN_DIM  4096
#define OUT_DIM 11008
#define NGROUPS 32

// ---- i8 GEMM geometry: 128x128 tile, BK=128 (= 1 scale group), 16x16x64 MFMA,
//      8 waves (2M x 4N), 2 blocks/CU. A staged in LDS (zero-conflict swizzle),
//      B fragments loaded DIRECTLY from global (L2) into registers, double-buffered.
//      A ds_reads issued just-in-time (2 at a time) to keep VGPR pressure < 128.
#define BM 128
#define BN 128
#define BKB 128                // i8 elems (=bytes) per row per K-tile = one quant group
#define THREADS 512
#define NKT   (IN_DIM / BKB)   // 32 K-tiles
#define BUFB  16384            // bytes per LDS buffer (A only: 128 rows x 128 B)

using f32x4  = __attribute__((ext_vector_type(4))) float;
using i32x4  = __attribute__((ext_vector_type(4))) int;
using bf16x8 = __attribute__((ext_vector_type(8))) short;

typedef __attribute__((address_space(3))) char as3c;

static __device__ __forceinline__ short f2bf(float f) {
    union { float f; unsigned u; } v; v.f = f;
    unsigned r = v.u + 0x7FFFu + ((v.u >> 16) & 1u);
    return (short)(r >> 16);
}

static __device__ __forceinline__ int pack4(int a, int b, int c, int d) {
    return (a & 255) | ((b & 255) << 8) | ((c & 255) << 16) | ((d & 255) << 24);
}

#define SB0 __builtin_amdgcn_sched_barrier(0)
#define LDSRO(dst, addr, off) asm volatile("ds_read_b128 %0, %1 offset:" #off : "=v"(dst) : "v"(addr))
#define WAITL(n) do { asm volatile("s_waitcnt lgkmcnt(" #n ")"); SB0; } while (0)
#define WAITV(n) do { asm volatile("s_waitcnt vmcnt(" #n ")");  SB0; } while (0)

// ---- pass 0a: per-token i8 quant of x/s; sx[row] = max|x/s| / 127 ----
__global__ __launch_bounds__(256) void prep_a_kernel(
    const float* __restrict__ x, const float* __restrict__ s,
    char* __restrict__ Aq, float* __restrict__ sx)
{
    const int row = blockIdx.x, t = threadIdx.x;
    const float* xp = x + (size_t)row * IN_DIM + t * 16;
    const float* sp = s + t * 16;
    f32x4 v[4];
    float m = 0.f;
    #pragma unroll
    for (int q = 0; q < 4; ++q) {
        f32x4 xv = *(const f32x4*)(xp + q * 4);
        f32x4 sv = *(const f32x4*)(sp + q * 4);
        #pragma unroll
        for (int e = 0; e < 4; ++e) {
            v[q][e] = xv[e] / sv[e];
            m = fmaxf(m, fabsf(v[q][e]));
        }
    }
    #pragma unroll
    for (int off = 32; off; off >>= 1) m = fmaxf(m, __shfl_xor(m, off));
    __shared__ float wm[4];
    if ((t & 63) == 0) wm[t >> 6] = m;
    __syncthreads();
    m = fmaxf(fmaxf(wm[0], wm[1]), fmaxf(wm[2], wm[3]));
    m = fmaxf(m, 1e-20f);
    const float inv = 127.0f / m;
    i32x4 pk;
    #pragma unroll
    for (int q = 0; q < 4; ++q)
        pk[q] = pack4((int)rintf(v[q][0] * inv), (int)rintf(v[q][1] * inv),
                      (int)rintf(v[q][2] * inv), (int)rintf(v[q][3] * inv));
    ((i32x4*)(Aq + (size_t)row * IN_DIM))[t] = pk;
    if (t == 0) sx[row] = m * (1.0f / 127.0f);
}

// ---- pass 0b: w_q i32 -> i8 (exact) ----
__global__ __launch_bounds__(256) void prep_b_kernel(
    const int* __restrict__ wq, char* __restrict__ Bq)
{
    const int idx = blockIdx.x * 256 + threadIdx.x;   // 16 elems each
    const int* wp = wq + (size_t)idx * 16;
    i32x4 w0 = *(const i32x4*)wp, w1 = *(const i32x4*)(wp + 4);
    i32x4 w2 = *(const i32x4*)(wp + 8), w3 = *(const i32x4*)(wp + 12);
    i32x4 pk;
    pk[0] = pack4(w0[0], w0[1], w0[2], w0[3]);
    pk[1] = pack4(w1[0], w1[1], w1[2], w1[3]);
    pk[2] = pack4(w2[0], w2[1], w2[2], w2[3]);
    pk[3] = pack4(w3[0], w3[1], w3[2], w3[3]);
    ((i32x4*)Bq)[idx] = pk;
}

// ---- pass 0c: transpose scales [O][G] -> scT [G][O] ----
__global__ __launch_bounds__(256) void prep_sc_kernel(
    const float* __restrict__ scales, float* __restrict__ scT)
{
    const int idx = blockIdx.x * 256 + threadIdx.x;
    const int g = idx / OUT_DIM;
    const int o = idx - g * OUT_DIM;
    scT[idx] = scales[o * NGROUPS + g];
}

// ---- 128x128 i8 GEMM, A via LDS, B direct-from-global to regs ----
__global__ __launch_bounds__(THREADS, 4) void awq_gemm_i8(
    const char* __restrict__ Aq, const char* __restrict__ Bq,
    const float* __restrict__ scT, const float* __restrict__ sx,
    const float* __restrict__ bias, float* __restrict__ out)
{
    // per-XCD block map (rb&7 -> XCD round-robin)
    const int rb = blockIdx.x;                  // grid 1408 = 8 * 176
    const int bm = (rb >> 3) & 15;              // 0..15
    const int bn = (((rb >> 3) >> 4) << 3) + (rb & 7);  // 0..87
    if (bn >= OUT_DIM / BN) return;             // 32 dead pad blocks

    __shared__ char smem[2 * BUFB];             // 32 KB (A only)
    as3c* ldsb = (as3c*)smem;
    const unsigned lbase = (unsigned)(size_t)ldsb;

    const int tid  = threadIdx.x;
    const int lane = tid & 63;
    const int w    = tid >> 6;        // wave 0..7
    const int wr   = w >> 2;          // 0..1 (M: 2 x 64)
    const int wc   = w & 3;           // 0..3 (N: 4 x 32)
    const int fr   = lane & 15;
    const int fko  = lane >> 4;       // 0..3 (16B k-quarter within 64-k chunk)

    // A fragment LDS read bases (buffer 0); granule slot g holds global granule g^(fr&7)
    const int h7 = fr & 7;
    const unsigned swz0 = (unsigned)(((0 * 4 + fko) ^ h7) * 16);
    const unsigned swz1 = (unsigned)(((1 * 4 + fko) ^ h7) * 16);
    const unsigned aB0 = lbase + (wr * 64 + fr) * 128 + swz0;   // + i*2048 (+16384 for buf1)
    const unsigned aB1 = lbase + (wr * 64 + fr) * 128 + swz1;

    // A staging: thread -> row tid>>3 (0..63) per sweep, granule tid&7 pre-swizzled
    const int srow = tid >> 3;
    const int sg   = ((tid & 7) ^ (srow & 7)) * 16;
    const char* aSrc = Aq + (size_t)(bm * BM + srow) * IN_DIM + sg;

    // scale source: per-lane column; +16 floats for j=1
    const float* scp = scT + bn * BN + wc * 32 + fr;

    // B fragment global pointers: lane reads Bq[col][k..k+16), col = wc*32 + j*16 + fr
    const char* bfp0 = Bq + (size_t)(bn * BN + wc * 32 + fr) * IN_DIM + fko * 16;  // j=0
    const char* bfp1 = bfp0 + (size_t)16 * IN_DIM;                                  // j=1

#define STG_A(Q, OFFB, P) __builtin_amdgcn_global_load_lds( \
    (const __attribute__((address_space(1))) void*)(const void*)(aStg + (OFFB) + (size_t)((Q) * 64) * IN_DIM), \
    (__attribute__((address_space(3))) void*)(ldsb + (P) * BUFB + (Q) * 8192 + tid * 16), 16, 0, 0)

#define BFRAG4(D00, D01, D10, D11, O0, O1) do { \
    asm volatile("global_load_dwordx4 %0, %1, off offset:" #O0 : "=v"(D00) : "v"(bfp0)); \
    asm volatile("global_load_dwordx4 %0, %1, off offset:" #O1 : "=v"(D01) : "v"(bfp0)); \
    asm volatile("global_load_dwordx4 %0, %1, off offset:" #O0 : "=v"(D10) : "v"(bfp1)); \
    asm volatile("global_load_dwordx4 %0, %1, off offset:" #O1 : "=v"(D11) : "v"(bfp1)); \
    SB0; } while (0)

#define SCV(D0, D1, PTR) do { \
    asm volatile("global_load_dword %0, %1, off" : "=v"(D0) : "v"(PTR)); \
    asm volatile("global_load_dword %0, %1, off" : "=v"(D1) : "v"((PTR) + 16)); \
    SB0; } while (0)

// one 16-row M-slab: 4 MFMAs (2 j-cols x 2 k-chunks) + inline dequant into f32 acc
#define MMI(A0, A1, B00, B01, B10, B11, F0, F1) do { \
    i32x4 t0 = __builtin_amdgcn_mfma_i32_16x16x64_i8(A0, B00, (i32x4){0,0,0,0}, 0, 0, 0); \
    t0       = __builtin_amdgcn_mfma_i32_16x16x64_i8(A1, B01, t0, 0, 0, 0); \
    i32x4 t1 = __builtin_amdgcn_mfma_i32_16x16x64_i8(A0, B10, (i32x4){0,0,0,0}, 0, 0, 0); \
    t1       = __builtin_amdgcn_mfma_i32_16x16x64_i8(A1, B11, t1, 0, 0, 0); \
    _Pragma("unroll") \
    for (int e = 0; e < 4; ++e) { \
        F0[e] += (float)t0[e] * c0; \
        F1[e] += (float)t1[e] * c1; \
    } } while (0)

    f32x4 accf[4][2];
    #pragma unroll
    for (int i = 0; i < 4; ++i) {
        accf[i][0] = (f32x4){0.f, 0.f, 0.f, 0.f};
        accf[i][1] = (f32x4){0.f, 0.f, 0.f, 0.f};
    }

    i32x4 b0_00, b0_01, b0_10, b0_11;   // B frags for even tiles
    i32x4 b1_00, b1_01, b1_10, b1_11;   // B frags for odd tiles
    float c0, c1, n0 = 0.f, n1 = 0.f;

    const char*  aStg = aSrc;
    const float* scN  = scp + OUT_DIM;   // scales for group t+1

    // prologue ledger: STG0[2], B0[4], SCV[2], STG1[2] -> WAITV(2) keeps STG1
    STG_A(0, 0, 0); STG_A(1, 0, 0);
    SB0;
    BFRAG4(b0_00, b0_01, b0_10, b0_11, 0, 64);
    SCV(c0, c1, scp);
    STG_A(0, 128, 1); STG_A(1, 128, 1);
    SB0;
    WAITV(2);
    __builtin_amdgcn_s_barrier();
    SB0;

    for (int it = 0; it < NKT / 2; ++it) {
        const bool last = (it == NKT / 2 - 1);
        i32x4 a00, a01, a10, a11, a20, a21, a30, a31;

        // ======== tile 2*it (buf0, b0_*) ========
        LDSRO(a00, aB0, 0);    LDSRO(a01, aB1, 0);
        LDSRO(a10, aB0, 2048); LDSRO(a11, aB1, 2048);
        BFRAG4(b1_00, b1_01, b1_10, b1_11, 128, 192);   // prefetch tile 2it+1 B
        SCV(n0, n1, scN);                               // prefetch group 2it+1 scales
        __builtin_amdgcn_s_setprio(1);
        WAITL(2);   // slab0 landed
        LDSRO(a20, aB0, 4096); LDSRO(a21, aB1, 4096);
        MMI(a00, a01, b0_00, b0_01, b0_10, b0_11, accf[0][0], accf[0][1]);
        WAITL(2);   // slab1 landed (in-order)
        LDSRO(a30, aB0, 6144); LDSRO(a31, aB1, 6144);
        MMI(a10, a11, b0_00, b0_01, b0_10, b0_11, accf[1][0], accf[1][1]);
        WAITL(2);   // slab2 landed
        MMI(a20, a21, b0_00, b0_01, b0_10, b0_11, accf[2][0], accf[2][1]);
        WAITL(0);   // slab3 landed; all reads of buf0 done (this wave)
        __builtin_amdgcn_s_barrier();   // all waves done reading buf0 -> safe to restage
        SB0;
        if (!last) { STG_A(0, 256, 0); STG_A(1, 256, 0); }   // tile 2it+2 -> buf0
        SB0;        // pin restage above the gate (intrinsics must not sink past WAITV)
        MMI(a30, a31, b0_00, b0_01, b0_10, b0_11, accf[3][0], accf[3][1]);
        __builtin_amdgcn_s_setprio(0);
        // gate: retire STG(2it+1)[2] + B(2it+1)[4] + SCV[2], keep STG(2it+2)[2]
        if (!last) { WAITV(2); } else { WAITV(0); }
        __builtin_amdgcn_s_barrier();
        SB0;
        c0 = n0; c1 = n1;

        // ======== tile 2*it+1 (buf1, b1_*) ========
        LDSRO(a00, aB0, 16384); LDSRO(a01, aB1, 16384);
        LDSRO(a10, aB0, 18432); LDSRO(a11, aB1, 18432);
        if (!last) { BFRAG4(b0_00, b0_01, b0_10, b0_11, 256, 320); SCV(n0, n1, scN + OUT_DIM); }
        __builtin_amdgcn_s_setprio(1);
        WAITL(2);
        LDSRO(a20, aB0, 20480); LDSRO(a21, aB1, 20480);
        MMI(a00, a01, b1_00, b1_01, b1_10, b1_11, accf[0][0], accf[0][1]);
        WAITL(2);
        LDSRO(a30, aB0, 22528); LDSRO(a31, aB1, 22528);
        MMI(a10, a11, b1_00, b1_01, b1_10, b1_11, accf[1][0], accf[1][1]);
        WAITL(2);
        MMI(a20, a21, b1_00, b1_01, b1_10, b1_11, accf[2][0], accf[2][1]);
        WAITL(0);
        __builtin_amdgcn_s_barrier();
        SB0;
        if (!last) { STG_A(0, 384, 1); STG_A(1, 384, 1); }   // tile 2it+3 -> buf1
        SB0;
        MMI(a30, a31, b1_00, b1_01, b1_10, b1_11, accf[3][0], accf[3][1]);
        __builtin_amdgcn_s_setprio(0);
        if (!last) { WAITV(2); } else { WAITV(0); }
        __builtin_amdgcn_s_barrier();
        SB0;
        if (!last) { c0 = n0; c1 = n1; }

        aStg += 256; scN += 2 * OUT_DIM;
        bfp0 += 256; bfp1 += 256;
    }

    // ---- epilogue: * sx[row], + bias[col] ----
    #pragma unroll
    for (int i = 0; i < 4; ++i) {
        const int row = bm * BM + wr * 64 + i * 16 + fko * 4;
        const f32x4 sxv = *(const f32x4*)(sx + row);
        #pragma unroll
        for (int j = 0; j < 2; ++j) {
            const int col = bn * BN + wc * 32 + j * 16 + fr;
            const float bv = bias[col];
            #pragma unroll
            for (int e = 0; e < 4; ++e)
                out[(size_t)(row + e) * OUT_DIM + col] = accf[i][j][e] * sxv[e] + bv;
        }
    }

#undef STG_A
#undef BFRAG4
#undef SCV
#undef MMI
}

// ---- fallback (no workspace): round-1 proven kernel ----
__global__ __launch_bounds__(256) void awq_gemm_fb(
    const float* __restrict__ x, const int* __restrict__ wq,
    const float* __restrict__ scales, const float* __restrict__ s,
    const float* __restrict__ bias, float* __restrict__ out)
{
    __shared__ short As[128][32];
    __shared__ short Bs[128][32];
    const int tid = threadIdx.x, lane = tid & 63, wave = tid >> 6;
    const int nbn = OUT_DIM / 128;
    const int bm = blockIdx.x / nbn, bn = blockIdx.x % nbn;
    const int srow = tid >> 1, scol = (tid & 1) * 16;
    const int wm = (wave >> 1) * 64, wn = (wave & 1) * 64;
    f32x4 acc[4][4];
    #pragma unroll
    for (int i = 0; i < 4; ++i)
        #pragma unroll
        for (int j = 0; j < 4; ++j) acc[i][j] = (f32x4){0.f, 0.f, 0.f, 0.f};
    const float* xrow = x + (size_t)(bm * 128 + srow) * IN_DIM;
    const int* wrow = wq + (size_t)(bn * 128 + srow) * IN_DIM;
    const float* scrow = scales + (size_t)(bn * 128 + srow) * NGROUPS;
    const int fr = lane & 15, fk = (lane >> 4) * 8, fq = lane >> 4;
    for (int kt = 0; kt < IN_DIM / 32; ++kt) {
        const int k0 = kt * 32;
        {
            const float* xp = xrow + k0 + scol;
            const float* sp = s + k0 + scol;
            short tmp[16];
            #pragma unroll
            for (int q = 0; q < 4; ++q) {
                f32x4 xv = *(const f32x4*)(xp + q * 4);
                f32x4 sv = *(const f32x4*)(sp + q * 4);
                #pragma unroll
                for (int e = 0; e < 4; ++e) tmp[q * 4 + e] = f2bf(xv[e] / sv[e]);
            }
            #pragma unroll
            for (int e = 0; e < 16; ++e) As[srow][scol + e] = tmp[e];
        }
        {
            const float sc = scrow[kt >> 2];
            const int* wp = wrow + k0 + scol;
            short tmp[16];
            #pragma unroll
            for (int q = 0; q < 4; ++q) {
                i32x4 wv = *(const i32x4*)(wp + q * 4);
                #pragma unroll
                for (int e = 0; e < 4; ++e) tmp[q * 4 + e] = f2bf((float)wv[e] * sc);
            }
            #pragma unroll
            for (int e = 0; e < 16; ++e) Bs[srow][scol + e] = tmp[e];
        }
        __syncthreads();
        bf16x8 a[4], b[4];
        #pragma unroll
        for (int i = 0; i < 4; ++i) a[i] = *(const bf16x8*)&As[wm + i * 16 + fr][fk];
        #pragma unroll
        for (int j = 0; j < 4; ++j) b[j] = *(const bf16x8*)&Bs[wn + j * 16 + fr][fk];
        #pragma unroll
        for (int i = 0; i < 4; ++i)
            #pragma unroll
            for (int j = 0; j < 4; ++j)
                acc[i][j] = __builtin_amdgcn_mfma_f32_16x16x32_bf16(a[i], b[j], acc[i][j], 0, 0, 0);
        __syncthreads();
    }
    #pragma unroll
    for (int i = 0; i < 4; ++i) {
        const int row = bm * 128 + wm + i * 16 + fq * 4;
        #pragma unroll
        for (int j = 0; j < 4; ++j) {
            const int col = bn * 128 + wn + j * 16 + fr;
            const float bv = bias[col];
            #pragma unroll
            for (int e = 0; e < 4; ++e)
                out[(size_t)(row + e) * OUT_DIM + col] = acc[i][j][e] + bv;
        }
    }
}

extern "C" void kernel_launch(void* const* d_in, const int* in_sizes, int n_in,
                              void* d_out, int out_size, void* d_ws, size_t ws_size,
                              hipStream_t stream) {
    const float* x      = (const float*)d_in[0];
    const int*   wq     = (const int*)  d_in[1];
    const float* scales = (const float*)d_in[2];
    const float* s      = (const float*)d_in[3];
    const float* bias   = (const float*)d_in[4];
    float* out = (float*)d_out;

    // ws layout (16B-aligned): Aq 8MB | sx 8KB | Bq 43MB | scT 1.4MB
    const size_t off_sx = (size_t)TOKENS * IN_DIM;             // 8388608
    const size_t off_bq = off_sx + 8192;
    const size_t off_sc = off_bq + (size_t)OUT_DIM * IN_DIM;
    const size_t need   = off_sc + (size_t)OUT_DIM * NGROUPS * 4;  // ~54.9MB

    if (ws_size >= need) {
        char*  Aq  = (char*)d_ws;
        float* sxw = (float*)((char*)d_ws + off_sx);
        char*  Bq  = (char*)d_ws + off_bq;
        float* scT = (float*)((char*)d_ws + off_sc);
        prep_a_kernel<<<TOKENS, 256, 0, stream>>>(x, s, Aq, sxw);
        prep_b_kernel<<<OUT_DIM * IN_DIM / 16 / 256, 256, 0, stream>>>(wq, Bq);
        prep_sc_kernel<<<OUT_DIM * NGROUPS / 256, 256, 0, stream>>>(scales, scT);
        awq_gemm_i8<<<1408, THREADS, 0, stream>>>(Aq, Bq, scT, sxw, bias, out);
    } else {
        awq_gemm_fb<<<(TOKENS / 128) * (OUT_DIM / 128), 256, 0, stream>>>(x, wq, scales, s, bias, out);
    }
}

// Round 5
// 306.032 us; speedup vs baseline: 1.3384x; 1.3384x over previous
//
#include <hip/hip_runtime.h>
#include <hip/hip_bf16.h>

#define TOKENS  2048
#define IN_DIM  4096
#define OUT_DIM 11008
#define NGROUPS 32

// ---- i8 GEMM geometry: 128x128 tile, BK=128 (= 1 scale group), 16x16x64 MFMA,
//      8 waves (2M x 4N), 2 blocks/CU. A staged in LDS (zero-conflict swizzle),
//      B fragments loaded DIRECTLY from global (L2) into registers, double-buffered.
//      A ds_reads issued just-in-time (2 at a time) to keep VGPR pressure < 128.
//      NOTE: __launch_bounds__ 2nd arg acts as BLOCKS/CU here: (512,4) capped VGPR
//      at 64 and spilled 450MB to scratch (r4: WRITE_SIZE 540MB, VGPR=64, 377us).
//      (512,2) -> 16 waves/CU -> 128-VGPR cap, fits the ~108-reg live set.
#define BM 128
#define BN 128
#define BKB 128                // i8 elems (=bytes) per row per K-tile = one quant group
#define THREADS 512
#define NKT   (IN_DIM / BKB)   // 32 K-tiles
#define BUFB  16384            // bytes per LDS buffer (A only: 128 rows x 128 B)

using f32x4  = __attribute__((ext_vector_type(4))) float;
using i32x4  = __attribute__((ext_vector_type(4))) int;
using bf16x8 = __attribute__((ext_vector_type(8))) short;

typedef __attribute__((address_space(3))) char as3c;

static __device__ __forceinline__ short f2bf(float f) {
    union { float f; unsigned u; } v; v.f = f;
    unsigned r = v.u + 0x7FFFu + ((v.u >> 16) & 1u);
    return (short)(r >> 16);
}

static __device__ __forceinline__ int pack4(int a, int b, int c, int d) {
    return (a & 255) | ((b & 255) << 8) | ((c & 255) << 16) | ((d & 255) << 24);
}

#define SB0 __builtin_amdgcn_sched_barrier(0)
#define LDSRO(dst, addr, off) asm volatile("ds_read_b128 %0, %1 offset:" #off : "=v"(dst) : "v"(addr))
#define WAITL(n) do { asm volatile("s_waitcnt lgkmcnt(" #n ")"); SB0; } while (0)
#define WAITV(n) do { asm volatile("s_waitcnt vmcnt(" #n ")");  SB0; } while (0)

// ---- pass 0a: per-token i8 quant of x/s; sx[row] = max|x/s| / 127 ----
__global__ __launch_bounds__(256) void prep_a_kernel(
    const float* __restrict__ x, const float* __restrict__ s,
    char* __restrict__ Aq, float* __restrict__ sx)
{
    const int row = blockIdx.x, t = threadIdx.x;
    const float* xp = x + (size_t)row * IN_DIM + t * 16;
    const float* sp = s + t * 16;
    f32x4 v[4];
    float m = 0.f;
    #pragma unroll
    for (int q = 0; q < 4; ++q) {
        f32x4 xv = *(const f32x4*)(xp + q * 4);
        f32x4 sv = *(const f32x4*)(sp + q * 4);
        #pragma unroll
        for (int e = 0; e < 4; ++e) {
            v[q][e] = xv[e] / sv[e];
            m = fmaxf(m, fabsf(v[q][e]));
        }
    }
    #pragma unroll
    for (int off = 32; off; off >>= 1) m = fmaxf(m, __shfl_xor(m, off));
    __shared__ float wm[4];
    if ((t & 63) == 0) wm[t >> 6] = m;
    __syncthreads();
    m = fmaxf(fmaxf(wm[0], wm[1]), fmaxf(wm[2], wm[3]));
    m = fmaxf(m, 1e-20f);
    const float inv = 127.0f / m;
    i32x4 pk;
    #pragma unroll
    for (int q = 0; q < 4; ++q)
        pk[q] = pack4((int)rintf(v[q][0] * inv), (int)rintf(v[q][1] * inv),
                      (int)rintf(v[q][2] * inv), (int)rintf(v[q][3] * inv));
    ((i32x4*)(Aq + (size_t)row * IN_DIM))[t] = pk;
    if (t == 0) sx[row] = m * (1.0f / 127.0f);
}

// ---- pass 0b: w_q i32 -> i8 (exact) ----
__global__ __launch_bounds__(256) void prep_b_kernel(
    const int* __restrict__ wq, char* __restrict__ Bq)
{
    const int idx = blockIdx.x * 256 + threadIdx.x;   // 16 elems each
    const int* wp = wq + (size_t)idx * 16;
    i32x4 w0 = *(const i32x4*)wp, w1 = *(const i32x4*)(wp + 4);
    i32x4 w2 = *(const i32x4*)(wp + 8), w3 = *(const i32x4*)(wp + 12);
    i32x4 pk;
    pk[0] = pack4(w0[0], w0[1], w0[2], w0[3]);
    pk[1] = pack4(w1[0], w1[1], w1[2], w1[3]);
    pk[2] = pack4(w2[0], w2[1], w2[2], w2[3]);
    pk[3] = pack4(w3[0], w3[1], w3[2], w3[3]);
    ((i32x4*)Bq)[idx] = pk;
}

// ---- pass 0c: transpose scales [O][G] -> scT [G][O] ----
__global__ __launch_bounds__(256) void prep_sc_kernel(
    const float* __restrict__ scales, float* __restrict__ scT)
{
    const int idx = blockIdx.x * 256 + threadIdx.x;
    const int g = idx / OUT_DIM;
    const int o = idx - g * OUT_DIM;
    scT[idx] = scales[o * NGROUPS + g];
}

// ---- 128x128 i8 GEMM, A via LDS, B direct-from-global to regs ----
__global__ __launch_bounds__(THREADS, 2) void awq_gemm_i8(
    const char* __restrict__ Aq, const char* __restrict__ Bq,
    const float* __restrict__ scT, const float* __restrict__ sx,
    const float* __restrict__ bias, float* __restrict__ out)
{
    // per-XCD block map (rb&7 -> XCD round-robin)
    const int rb = blockIdx.x;                  // grid 1408 = 8 * 176
    const int bm = (rb >> 3) & 15;              // 0..15
    const int bn = (((rb >> 3) >> 4) << 3) + (rb & 7);  // 0..87
    if (bn >= OUT_DIM / BN) return;             // 32 dead pad blocks

    __shared__ char smem[2 * BUFB];             // 32 KB (A only)
    as3c* ldsb = (as3c*)smem;
    const unsigned lbase = (unsigned)(size_t)ldsb;

    const int tid  = threadIdx.x;
    const int lane = tid & 63;
    const int w    = tid >> 6;        // wave 0..7
    const int wr   = w >> 2;          // 0..1 (M: 2 x 64)
    const int wc   = w & 3;           // 0..3 (N: 4 x 32)
    const int fr   = lane & 15;
    const int fko  = lane >> 4;       // 0..3 (16B k-quarter within 64-k chunk)

    // A fragment LDS read bases (buffer 0); granule slot g holds global granule g^(fr&7)
    const int h7 = fr & 7;
    const unsigned swz0 = (unsigned)(((0 * 4 + fko) ^ h7) * 16);
    const unsigned swz1 = (unsigned)(((1 * 4 + fko) ^ h7) * 16);
    const unsigned aB0 = lbase + (wr * 64 + fr) * 128 + swz0;   // + i*2048 (+16384 for buf1)
    const unsigned aB1 = lbase + (wr * 64 + fr) * 128 + swz1;

    // A staging: thread -> row tid>>3 (0..63) per sweep, granule tid&7 pre-swizzled
    const int srow = tid >> 3;
    const int sg   = ((tid & 7) ^ (srow & 7)) * 16;
    const char* aSrc = Aq + (size_t)(bm * BM + srow) * IN_DIM + sg;

    // scale source: per-lane column; +16 floats for j=1
    const float* scp = scT + bn * BN + wc * 32 + fr;

    // B fragment global pointers: lane reads Bq[col][k..k+16), col = wc*32 + j*16 + fr
    const char* bfp0 = Bq + (size_t)(bn * BN + wc * 32 + fr) * IN_DIM + fko * 16;  // j=0
    const char* bfp1 = bfp0 + (size_t)16 * IN_DIM;                                  // j=1

#define STG_A(Q, OFFB, P) __builtin_amdgcn_global_load_lds( \
    (const __attribute__((address_space(1))) void*)(const void*)(aStg + (OFFB) + (size_t)((Q) * 64) * IN_DIM), \
    (__attribute__((address_space(3))) void*)(ldsb + (P) * BUFB + (Q) * 8192 + tid * 16), 16, 0, 0)

#define BFRAG4(D00, D01, D10, D11, O0, O1) do { \
    asm volatile("global_load_dwordx4 %0, %1, off offset:" #O0 : "=v"(D00) : "v"(bfp0)); \
    asm volatile("global_load_dwordx4 %0, %1, off offset:" #O1 : "=v"(D01) : "v"(bfp0)); \
    asm volatile("global_load_dwordx4 %0, %1, off offset:" #O0 : "=v"(D10) : "v"(bfp1)); \
    asm volatile("global_load_dwordx4 %0, %1, off offset:" #O1 : "=v"(D11) : "v"(bfp1)); \
    SB0; } while (0)

#define SCV(D0, D1, PTR) do { \
    asm volatile("global_load_dword %0, %1, off" : "=v"(D0) : "v"(PTR)); \
    asm volatile("global_load_dword %0, %1, off" : "=v"(D1) : "v"((PTR) + 16)); \
    SB0; } while (0)

// one 16-row M-slab: 4 MFMAs (2 j-cols x 2 k-chunks) + inline dequant into f32 acc
#define MMI(A0, A1, B00, B01, B10, B11, F0, F1) do { \
    i32x4 t0 = __builtin_amdgcn_mfma_i32_16x16x64_i8(A0, B00, (i32x4){0,0,0,0}, 0, 0, 0); \
    t0       = __builtin_amdgcn_mfma_i32_16x16x64_i8(A1, B01, t0, 0, 0, 0); \
    i32x4 t1 = __builtin_amdgcn_mfma_i32_16x16x64_i8(A0, B10, (i32x4){0,0,0,0}, 0, 0, 0); \
    t1       = __builtin_amdgcn_mfma_i32_16x16x64_i8(A1, B11, t1, 0, 0, 0); \
    _Pragma("unroll") \
    for (int e = 0; e < 4; ++e) { \
        F0[e] += (float)t0[e] * c0; \
        F1[e] += (float)t1[e] * c1; \
    } } while (0)

    f32x4 accf[4][2];
    #pragma unroll
    for (int i = 0; i < 4; ++i) {
        accf[i][0] = (f32x4){0.f, 0.f, 0.f, 0.f};
        accf[i][1] = (f32x4){0.f, 0.f, 0.f, 0.f};
    }

    i32x4 b0_00, b0_01, b0_10, b0_11;   // B frags for even tiles
    i32x4 b1_00, b1_01, b1_10, b1_11;   // B frags for odd tiles
    float c0, c1, n0 = 0.f, n1 = 0.f;

    const char*  aStg = aSrc;
    const float* scN  = scp + OUT_DIM;   // scales for group t+1

    // prologue ledger: STG0[2], B0[4], SCV[2], STG1[2] -> WAITV(2) keeps STG1
    STG_A(0, 0, 0); STG_A(1, 0, 0);
    SB0;
    BFRAG4(b0_00, b0_01, b0_10, b0_11, 0, 64);
    SCV(c0, c1, scp);
    STG_A(0, 128, 1); STG_A(1, 128, 1);
    SB0;
    WAITV(2);
    __builtin_amdgcn_s_barrier();
    SB0;

    for (int it = 0; it < NKT / 2; ++it) {
        const bool last = (it == NKT / 2 - 1);
        i32x4 a00, a01, a10, a11, a20, a21, a30, a31;

        // ======== tile 2*it (buf0, b0_*) ========
        LDSRO(a00, aB0, 0);    LDSRO(a01, aB1, 0);
        LDSRO(a10, aB0, 2048); LDSRO(a11, aB1, 2048);
        BFRAG4(b1_00, b1_01, b1_10, b1_11, 128, 192);   // prefetch tile 2it+1 B
        SCV(n0, n1, scN);                               // prefetch group 2it+1 scales
        __builtin_amdgcn_s_setprio(1);
        WAITL(2);   // slab0 landed
        LDSRO(a20, aB0, 4096); LDSRO(a21, aB1, 4096);
        MMI(a00, a01, b0_00, b0_01, b0_10, b0_11, accf[0][0], accf[0][1]);
        WAITL(2);   // slab1 landed (in-order)
        LDSRO(a30, aB0, 6144); LDSRO(a31, aB1, 6144);
        MMI(a10, a11, b0_00, b0_01, b0_10, b0_11, accf[1][0], accf[1][1]);
        WAITL(2);   // slab2 landed
        MMI(a20, a21, b0_00, b0_01, b0_10, b0_11, accf[2][0], accf[2][1]);
        WAITL(0);   // slab3 landed; all reads of buf0 done (this wave)
        __builtin_amdgcn_s_barrier();   // all waves done reading buf0 -> safe to restage
        SB0;
        if (!last) { STG_A(0, 256, 0); STG_A(1, 256, 0); }   // tile 2it+2 -> buf0
        SB0;        // pin restage above the gate (intrinsics must not sink past WAITV)
        MMI(a30, a31, b0_00, b0_01, b0_10, b0_11, accf[3][0], accf[3][1]);
        __builtin_amdgcn_s_setprio(0);
        // gate: retire STG(2it+1)[2] + B(2it+1)[4] + SCV[2], keep STG(2it+2)[2]
        if (!last) { WAITV(2); } else { WAITV(0); }
        __builtin_amdgcn_s_barrier();
        SB0;
        c0 = n0; c1 = n1;

        // ======== tile 2*it+1 (buf1, b1_*) ========
        LDSRO(a00, aB0, 16384); LDSRO(a01, aB1, 16384);
        LDSRO(a10, aB0, 18432); LDSRO(a11, aB1, 18432);
        if (!last) { BFRAG4(b0_00, b0_01, b0_10, b0_11, 256, 320); SCV(n0, n1, scN + OUT_DIM); }
        __builtin_amdgcn_s_setprio(1);
        WAITL(2);
        LDSRO(a20, aB0, 20480); LDSRO(a21, aB1, 20480);
        MMI(a00, a01, b1_00, b1_01, b1_10, b1_11, accf[0][0], accf[0][1]);
        WAITL(2);
        LDSRO(a30, aB0, 22528); LDSRO(a31, aB1, 22528);
        MMI(a10, a11, b1_00, b1_01, b1_10, b1_11, accf[1][0], accf[1][1]);
        WAITL(2);
        MMI(a20, a21, b1_00, b1_01, b1_10, b1_11, accf[2][0], accf[2][1]);
        WAITL(0);
        __builtin_amdgcn_s_barrier();
        SB0;
        if (!last) { STG_A(0, 384, 1); STG_A(1, 384, 1); }   // tile 2it+3 -> buf1
        SB0;
        MMI(a30, a31, b1_00, b1_01, b1_10, b1_11, accf[3][0], accf[3][1]);
        __builtin_amdgcn_s_setprio(0);
        if (!last) { WAITV(2); } else { WAITV(0); }
        __builtin_amdgcn_s_barrier();
        SB0;
        if (!last) { c0 = n0; c1 = n1; }

        aStg += 256; scN += 2 * OUT_DIM;
        bfp0 += 256; bfp1 += 256;
    }

    // ---- epilogue: * sx[row], + bias[col] ----
    #pragma unroll
    for (int i = 0; i < 4; ++i) {
        const int row = bm * BM + wr * 64 + i * 16 + fko * 4;
        const f32x4 sxv = *(const f32x4*)(sx + row);
        #pragma unroll
        for (int j = 0; j < 2; ++j) {
            const int col = bn * BN + wc * 32 + j * 16 + fr;
            const float bv = bias[col];
            #pragma unroll
            for (int e = 0; e < 4; ++e)
                out[(size_t)(row + e) * OUT_DIM + col] = accf[i][j][e] * sxv[e] + bv;
        }
    }

#undef STG_A
#undef BFRAG4
#undef SCV
#undef MMI
}

// ---- fallback (no workspace): round-1 proven kernel ----
__global__ __launch_bounds__(256) void awq_gemm_fb(
    const float* __restrict__ x, const int* __restrict__ wq,
    const float* __restrict__ scales, const float* __restrict__ s,
    const float* __restrict__ bias, float* __restrict__ out)
{
    __shared__ short As[128][32];
    __shared__ short Bs[128][32];
    const int tid = threadIdx.x, lane = tid & 63, wave = tid >> 6;
    const int nbn = OUT_DIM / 128;
    const int bm = blockIdx.x / nbn, bn = blockIdx.x % nbn;
    const int srow = tid >> 1, scol = (tid & 1) * 16;
    const int wm = (wave >> 1) * 64, wn = (wave & 1) * 64;
    f32x4 acc[4][4];
    #pragma unroll
    for (int i = 0; i < 4; ++i)
        #pragma unroll
        for (int j = 0; j < 4; ++j) acc[i][j] = (f32x4){0.f, 0.f, 0.f, 0.f};
    const float* xrow = x + (size_t)(bm * 128 + srow) * IN_DIM;
    const int* wrow = wq + (size_t)(bn * 128 + srow) * IN_DIM;
    const float* scrow = scales + (size_t)(bn * 128 + srow) * NGROUPS;
    const int fr = lane & 15, fk = (lane >> 4) * 8, fq = lane >> 4;
    for (int kt = 0; kt < IN_DIM / 32; ++kt) {
        const int k0 = kt * 32;
        {
            const float* xp = xrow + k0 + scol;
            const float* sp = s + k0 + scol;
            short tmp[16];
            #pragma unroll
            for (int q = 0; q < 4; ++q) {
                f32x4 xv = *(const f32x4*)(xp + q * 4);
                f32x4 sv = *(const f32x4*)(sp + q * 4);
                #pragma unroll
                for (int e = 0; e < 4; ++e) tmp[q * 4 + e] = f2bf(xv[e] / sv[e]);
            }
            #pragma unroll
            for (int e = 0; e < 16; ++e) As[srow][scol + e] = tmp[e];
        }
        {
            const float sc = scrow[kt >> 2];
            const int* wp = wrow + k0 + scol;
            short tmp[16];
            #pragma unroll
            for (int q = 0; q < 4; ++q) {
                i32x4 wv = *(const i32x4*)(wp + q * 4);
                #pragma unroll
                for (int e = 0; e < 4; ++e) tmp[q * 4 + e] = f2bf((float)wv[e] * sc);
            }
            #pragma unroll
            for (int e = 0; e < 16; ++e) Bs[srow][scol + e] = tmp[e];
        }
        __syncthreads();
        bf16x8 a[4], b[4];
        #pragma unroll
        for (int i = 0; i < 4; ++i) a[i] = *(const bf16x8*)&As[wm + i * 16 + fr][fk];
        #pragma unroll
        for (int j = 0; j < 4; ++j) b[j] = *(const bf16x8*)&Bs[wn + j * 16 + fr][fk];
        #pragma unroll
        for (int i = 0; i < 4; ++i)
            #pragma unroll
            for (int j = 0; j < 4; ++j)
                acc[i][j] = __builtin_amdgcn_mfma_f32_16x16x32_bf16(a[i], b[j], acc[i][j], 0, 0, 0);
        __syncthreads();
    }
    #pragma unroll
    for (int i = 0; i < 4; ++i) {
        const int row = bm * 128 + wm + i * 16 + fq * 4;
        #pragma unroll
        for (int j = 0; j < 4; ++j) {
            const int col = bn * 128 + wn + j * 16 + fr;
            const float bv = bias[col];
            #pragma unroll
            for (int e = 0; e < 4; ++e)
                out[(size_t)(row + e) * OUT_DIM + col] = acc[i][j][e] + bv;
        }
    }
}

extern "C" void kernel_launch(void* const* d_in, const int* in_sizes, int n_in,
                              void* d_out, int out_size, void* d_ws, size_t ws_size,
                              hipStream_t stream) {
    const float* x      = (const float*)d_in[0];
    const int*   wq     = (const int*)  d_in[1];
    const float* scales = (const float*)d_in[2];
    const float* s      = (const float*)d_in[3];
    const float* bias   = (const float*)d_in[4];
    float* out = (float*)d_out;

    // ws layout (16B-aligned): Aq 8MB | sx 8KB | Bq 43MB | scT 1.4MB
    const size_t off_sx = (size_t)TOKENS * IN_DIM;             // 8388608
    const size_t off_bq = off_sx + 8192;
    const size_t off_sc = off_bq + (size_t)OUT_DIM * IN_DIM;
    const size_t need   = off_sc + (size_t)OUT_DIM * NGROUPS * 4;  // ~54.9MB

    if (ws_size >= need) {
        char*  Aq  = (char*)d_ws;
        float* sxw = (float*)((char*)d_ws + off_sx);
        char*  Bq  = (char*)d_ws + off_bq;
        float* scT = (float*)((char*)d_ws + off_sc);
        prep_a_kernel<<<TOKENS, 256, 0, stream>>>(x, s, Aq, sxw);
        prep_b_kernel<<<OUT_DIM * IN_DIM / 16 / 256, 256, 0, stream>>>(wq, Bq);
        prep_sc_kernel<<<OUT_DIM * NGROUPS / 256, 256, 0, stream>>>(scales, scT);
        awq_gemm_i8<<<1408, THREADS, 0, stream>>>(Aq, Bq, scT, sxw, bias, out);
    } else {
        awq_gemm_fb<<<(TOKENS / 128) * (OUT_DIM / 128), 256, 0, stream>>>(x, wq, scales, s, bias, out);
    }
}

// Round 6
// 265.226 us; speedup vs baseline: 1.5443x; 1.1539x over previous
//
#include <hip/hip_runtime.h>
#include <hip/hip_bf16.h>

#define TOKENS  2048
#define IN_DIM  4096
#define OUT_DIM 11008
#define NGROUPS 32

// ---- i8 GEMM geometry: 128x256 tile, BK=64 (half scale group), 16x16x64 MFMA,
//      8 waves of 64x64 (2M x 4N), 2 blocks/CU, both operands via LDS.
//      Round-5 lesson: B-direct-from-global = TA-port disaster (16 lines/instr,
//      MfmaUtil 14%). LDS broadcast is the right primitive; win comes from the
//      bigger tile: LDS bytes per 128^2-output drop 128KB -> 88KB (-31%).
//      Dequant per half-group (same scale both halves of group) = exact math.
#define BM 128
#define BN 256
#define BK 64                  // i8 elems (=bytes) per row per K-tile
#define THREADS 512
#define NT    (IN_DIM / BK)    // 64 K-tiles (2 per scale group)
#define ABYTES (BM * BK)       // 8192
#define BBYTES (BN * BK)       // 16384
#define BUFB  (ABYTES + BBYTES) // 24576 per buffer; x2 = 48KB -> 2 blocks/CU

using f32x4  = __attribute__((ext_vector_type(4))) float;
using i32x4  = __attribute__((ext_vector_type(4))) int;
using bf16x8 = __attribute__((ext_vector_type(8))) short;

typedef __attribute__((address_space(3))) char as3c;

static __device__ __forceinline__ short f2bf(float f) {
    union { float f; unsigned u; } v; v.f = f;
    unsigned r = v.u + 0x7FFFu + ((v.u >> 16) & 1u);
    return (short)(r >> 16);
}

static __device__ __forceinline__ int pack4(int a, int b, int c, int d) {
    return (a & 255) | ((b & 255) << 8) | ((c & 255) << 16) | ((d & 255) << 24);
}

#define SB0 __builtin_amdgcn_sched_barrier(0)
#define LDSRO(dst, addr, off) asm volatile("ds_read_b128 %0, %1 offset:" #off : "=v"(dst) : "v"(addr))
#define WAITL(n) do { asm volatile("s_waitcnt lgkmcnt(" #n ")"); SB0; } while (0)
#define WAITV(n) do { asm volatile("s_waitcnt vmcnt(" #n ")");  SB0; } while (0)

// ---- pass 0a: per-token i8 quant of x/s; sx[row] = max|x/s| / 127 ----
__global__ __launch_bounds__(256) void prep_a_kernel(
    const float* __restrict__ x, const float* __restrict__ s,
    char* __restrict__ Aq, float* __restrict__ sx)
{
    const int row = blockIdx.x, t = threadIdx.x;
    const float* xp = x + (size_t)row * IN_DIM + t * 16;
    const float* sp = s + t * 16;
    f32x4 v[4];
    float m = 0.f;
    #pragma unroll
    for (int q = 0; q < 4; ++q) {
        f32x4 xv = *(const f32x4*)(xp + q * 4);
        f32x4 sv = *(const f32x4*)(sp + q * 4);
        #pragma unroll
        for (int e = 0; e < 4; ++e) {
            v[q][e] = xv[e] / sv[e];
            m = fmaxf(m, fabsf(v[q][e]));
        }
    }
    #pragma unroll
    for (int off = 32; off; off >>= 1) m = fmaxf(m, __shfl_xor(m, off));
    __shared__ float wm[4];
    if ((t & 63) == 0) wm[t >> 6] = m;
    __syncthreads();
    m = fmaxf(fmaxf(wm[0], wm[1]), fmaxf(wm[2], wm[3]));
    m = fmaxf(m, 1e-20f);
    const float inv = 127.0f / m;
    i32x4 pk;
    #pragma unroll
    for (int q = 0; q < 4; ++q)
        pk[q] = pack4((int)rintf(v[q][0] * inv), (int)rintf(v[q][1] * inv),
                      (int)rintf(v[q][2] * inv), (int)rintf(v[q][3] * inv));
    ((i32x4*)(Aq + (size_t)row * IN_DIM))[t] = pk;
    if (t == 0) sx[row] = m * (1.0f / 127.0f);
}

// ---- pass 0b: w_q i32 -> i8 (exact) ----
__global__ __launch_bounds__(256) void prep_b_kernel(
    const int* __restrict__ wq, char* __restrict__ Bq)
{
    const int idx = blockIdx.x * 256 + threadIdx.x;   // 16 elems each
    const int* wp = wq + (size_t)idx * 16;
    i32x4 w0 = *(const i32x4*)wp, w1 = *(const i32x4*)(wp + 4);
    i32x4 w2 = *(const i32x4*)(wp + 8), w3 = *(const i32x4*)(wp + 12);
    i32x4 pk;
    pk[0] = pack4(w0[0], w0[1], w0[2], w0[3]);
    pk[1] = pack4(w1[0], w1[1], w1[2], w1[3]);
    pk[2] = pack4(w2[0], w2[1], w2[2], w2[3]);
    pk[3] = pack4(w3[0], w3[1], w3[2], w3[3]);
    ((i32x4*)Bq)[idx] = pk;
}

// ---- pass 0c: transpose scales [O][G] -> scT [G][O] ----
__global__ __launch_bounds__(256) void prep_sc_kernel(
    const float* __restrict__ scales, float* __restrict__ scT)
{
    const int idx = blockIdx.x * 256 + threadIdx.x;
    const int g = idx / OUT_DIM;
    const int o = idx - g * OUT_DIM;
    scT[idx] = scales[o * NGROUPS + g];
}

// ---- 128x256 i8 GEMM, A+B via LDS, 8 waves of 64x64 ----
__global__ __launch_bounds__(THREADS, 2) void awq_gemm_i8(
    const char* __restrict__ Aq, const char* __restrict__ Bq,
    const float* __restrict__ scT, const float* __restrict__ sx,
    const float* __restrict__ bias, float* __restrict__ out)
{
    // per-XCD block map: grid 768 = 8 * 96; bm 0..15, bn 0..47 (43 live)
    const int rb = blockIdx.x;
    const int bm = (rb >> 3) & 15;
    const int bn = (((rb >> 3) >> 4) << 3) + (rb & 7);
    if (bn >= OUT_DIM / BN) return;             // 80 dead pad blocks

    __shared__ char smem[2 * BUFB];             // 48 KB -> 2 blocks/CU
    as3c* ldsb = (as3c*)smem;
    const unsigned lbase = (unsigned)(size_t)ldsb;

    const int tid  = threadIdx.x;
    const int lane = tid & 63;
    const int w    = tid >> 6;        // wave 0..7
    const int wr   = w >> 2;          // 0..1 (M: 2 x 64)
    const int wc   = w & 3;           // 0..3 (N: 4 x 64)
    const int fr   = lane & 15;
    const int fko  = lane >> 4;       // 0..3 (16B k-quarter of the 64-K tile)

    // frag read bases; rows are 64B = 4 granules; slot g holds global granule
    // g ^ (row&3).  Stride-8 lane sets -> 4 slots x 2 lanes = 2-way = free.
    const unsigned sw4  = (unsigned)((fko ^ (fr & 3)) * 16);
    const unsigned aAddr = lbase + (unsigned)((wr * 64 + fr) * 64) + sw4;          // +i*1024 (+BUFB odd)
    const unsigned bAddr = lbase + ABYTES + (unsigned)((wc * 64 + fr) * 64) + sw4; // +j*1024 (+BUFB odd)

    // staging: thread -> row tid>>2 (0..127), granule (tid&3) pre-swizzled
    const int sr = tid >> 2;
    const int sg = ((tid & 3) ^ (sr & 3)) * 16;
    const char* aSrc  = Aq + (size_t)(bm * BM + sr) * IN_DIM + sg;
    const char* bSrc  = Bq + (size_t)(bn * BN + sr) * IN_DIM + sg;
    const char* bSrc2 = bSrc + (size_t)128 * IN_DIM;

    // scales: lane's 4 columns are wc*64 + j*16 + fr, j=0..3 (strides 64B)
    const float* scp = scT + bn * BN + wc * 64 + fr;

#define STG(PA, PB, PB2, P) do { \
    __builtin_amdgcn_global_load_lds((const __attribute__((address_space(1))) void*)(const void*)(PA), \
        (__attribute__((address_space(3))) void*)(ldsb + (P) * BUFB + tid * 16), 16, 0, 0); \
    __builtin_amdgcn_global_load_lds((const __attribute__((address_space(1))) void*)(const void*)(PB), \
        (__attribute__((address_space(3))) void*)(ldsb + (P) * BUFB + ABYTES + tid * 16), 16, 0, 0); \
    __builtin_amdgcn_global_load_lds((const __attribute__((address_space(1))) void*)(const void*)(PB2), \
        (__attribute__((address_space(3))) void*)(ldsb + (P) * BUFB + ABYTES + 8192 + tid * 16), 16, 0, 0); \
    SB0; } while (0)

#define SCV4(D0, D1, D2, D3, PTR) do { \
    asm volatile("global_load_dword %0, %1, off"            : "=v"(D0) : "v"(PTR)); \
    asm volatile("global_load_dword %0, %1, off offset:64"  : "=v"(D1) : "v"(PTR)); \
    asm volatile("global_load_dword %0, %1, off offset:128" : "=v"(D2) : "v"(PTR)); \
    asm volatile("global_load_dword %0, %1, off offset:192" : "=v"(D3) : "v"(PTR)); \
    SB0; } while (0)

// one j-column: 4 MFMAs (K=64 = full tile depth) + immediate half-group dequant
#define QUADJ(J, CJ) do { \
    i32x4 t0 = __builtin_amdgcn_mfma_i32_16x16x64_i8(a[0], b[J], (i32x4){0,0,0,0}, 0, 0, 0); \
    i32x4 t1 = __builtin_amdgcn_mfma_i32_16x16x64_i8(a[1], b[J], (i32x4){0,0,0,0}, 0, 0, 0); \
    i32x4 t2 = __builtin_amdgcn_mfma_i32_16x16x64_i8(a[2], b[J], (i32x4){0,0,0,0}, 0, 0, 0); \
    i32x4 t3 = __builtin_amdgcn_mfma_i32_16x16x64_i8(a[3], b[J], (i32x4){0,0,0,0}, 0, 0, 0); \
    _Pragma("unroll") \
    for (int e = 0; e < 4; ++e) { \
        accf[0][J][e] += (float)t0[e] * (CJ); \
        accf[1][J][e] += (float)t1[e] * (CJ); \
        accf[2][J][e] += (float)t2[e] * (CJ); \
        accf[3][J][e] += (float)t3[e] * (CJ); \
    } } while (0)

#define COMPUTE() do { \
    __builtin_amdgcn_s_setprio(1); \
    QUADJ(0, c0); QUADJ(1, c1); QUADJ(2, c2); QUADJ(3, c3); \
    __builtin_amdgcn_s_setprio(0); } while (0)

    f32x4 accf[4][4];
    #pragma unroll
    for (int i = 0; i < 4; ++i)
        #pragma unroll
        for (int j = 0; j < 4; ++j) accf[i][j] = (f32x4){0.f, 0.f, 0.f, 0.f};

    i32x4 a[4], b[4];
    float c0, c1, c2, c3, n0 = 0.f, n1 = 0.f, n2 = 0.f, n3 = 0.f;

    // prologue ledger: STG0[3], SCV[4], STG1[3] -> WAITV(3) keeps STG1
    STG(aSrc, bSrc, bSrc2, 0);
    SCV4(c0, c1, c2, c3, scp);
    STG(aSrc + BK, bSrc + BK, bSrc2 + BK, 1);
    WAITV(3);
    __builtin_amdgcn_s_barrier();
    SB0;

    const char*  aStg  = aSrc  + 2 * BK;
    const char*  bStg  = bSrc  + 2 * BK;
    const char*  bStg2 = bSrc2 + 2 * BK;
    const float* scN   = scp + OUT_DIM;     // scales for next group

    for (int p = 0; p < NT / 2; ++p) {      // one scale group per iteration
        const bool haveN = (p < NT / 2 - 1);

        // ======== even tile 2p (buf0) ========
        LDSRO(a[0], aAddr, 0);    LDSRO(a[1], aAddr, 1024);
        LDSRO(a[2], aAddr, 2048); LDSRO(a[3], aAddr, 3072);
        LDSRO(b[0], bAddr, 0);    LDSRO(b[1], bAddr, 1024);
        LDSRO(b[2], bAddr, 2048); LDSRO(b[3], bAddr, 3072);
        WAITL(0);
        __builtin_amdgcn_s_barrier();   // all waves done reading buf0 -> restage OK
        SB0;
        if (haveN) STG(aStg, bStg, bStg2, 0);   // tile 2p+2 -> buf0
        SB0;
        COMPUTE();
        // gate: retire STG(2p+1)[3], keep STG(2p+2)[3]
        if (haveN) { WAITV(3); } else { WAITV(0); }
        __builtin_amdgcn_s_barrier();
        SB0;

        // ======== odd tile 2p+1 (buf1) ========
        LDSRO(a[0], aAddr, 24576); LDSRO(a[1], aAddr, 25600);
        LDSRO(a[2], aAddr, 26624); LDSRO(a[3], aAddr, 27648);
        LDSRO(b[0], bAddr, 24576); LDSRO(b[1], bAddr, 25600);
        LDSRO(b[2], bAddr, 26624); LDSRO(b[3], bAddr, 27648);
        WAITL(0);
        __builtin_amdgcn_s_barrier();
        SB0;
        if (haveN) {
            SCV4(n0, n1, n2, n3, scN);                         // next-group scales
            STG(aStg + BK, bStg + BK, bStg2 + BK, 1);          // tile 2p+3 -> buf1
        }
        SB0;
        COMPUTE();
        // gate: retire STG(2p+2)[3] + SCV[4], keep STG(2p+3)[3]
        if (haveN) { WAITV(3); } else { WAITV(0); }
        __builtin_amdgcn_s_barrier();
        SB0;
        if (haveN) {
            c0 = n0; c1 = n1; c2 = n2; c3 = n3;
            aStg += 2 * BK; bStg += 2 * BK; bStg2 += 2 * BK; scN += OUT_DIM;
        }
    }

    // ---- epilogue: * sx[row], + bias[col] ----
    #pragma unroll
    for (int i = 0; i < 4; ++i) {
        const int row = bm * BM + wr * 64 + i * 16 + fko * 4;
        const f32x4 sxv = *(const f32x4*)(sx + row);
        #pragma unroll
        for (int j = 0; j < 4; ++j) {
            const int col = bn * BN + wc * 64 + j * 16 + fr;
            const float bv = bias[col];
            #pragma unroll
            for (int e = 0; e < 4; ++e)
                out[(size_t)(row + e) * OUT_DIM + col] = accf[i][j][e] * sxv[e] + bv;
        }
    }

#undef STG
#undef SCV4
#undef QUADJ
#undef COMPUTE
}

// ---- fallback (no workspace): round-1 proven kernel ----
__global__ __launch_bounds__(256) void awq_gemm_fb(
    const float* __restrict__ x, const int* __restrict__ wq,
    const float* __restrict__ scales, const float* __restrict__ s,
    const float* __restrict__ bias, float* __restrict__ out)
{
    __shared__ short As[128][32];
    __shared__ short Bs[128][32];
    const int tid = threadIdx.x, lane = tid & 63, wave = tid >> 6;
    const int nbn = OUT_DIM / 128;
    const int bm = blockIdx.x / nbn, bn = blockIdx.x % nbn;
    const int srow = tid >> 1, scol = (tid & 1) * 16;
    const int wm = (wave >> 1) * 64, wn = (wave & 1) * 64;
    f32x4 acc[4][4];
    #pragma unroll
    for (int i = 0; i < 4; ++i)
        #pragma unroll
        for (int j = 0; j < 4; ++j) acc[i][j] = (f32x4){0.f, 0.f, 0.f, 0.f};
    const float* xrow = x + (size_t)(bm * 128 + srow) * IN_DIM;
    const int* wrow = wq + (size_t)(bn * 128 + srow) * IN_DIM;
    const float* scrow = scales + (size_t)(bn * 128 + srow) * NGROUPS;
    const int fr = lane & 15, fk = (lane >> 4) * 8, fq = lane >> 4;
    for (int kt = 0; kt < IN_DIM / 32; ++kt) {
        const int k0 = kt * 32;
        {
            const float* xp = xrow + k0 + scol;
            const float* sp = s + k0 + scol;
            short tmp[16];
            #pragma unroll
            for (int q = 0; q < 4; ++q) {
                f32x4 xv = *(const f32x4*)(xp + q * 4);
                f32x4 sv = *(const f32x4*)(sp + q * 4);
                #pragma unroll
                for (int e = 0; e < 4; ++e) tmp[q * 4 + e] = f2bf(xv[e] / sv[e]);
            }
            #pragma unroll
            for (int e = 0; e < 16; ++e) As[srow][scol + e] = tmp[e];
        }
        {
            const float sc = scrow[kt >> 2];
            const int* wp = wrow + k0 + scol;
            short tmp[16];
            #pragma unroll
            for (int q = 0; q < 4; ++q) {
                i32x4 wv = *(const i32x4*)(wp + q * 4);
                #pragma unroll
                for (int e = 0; e < 4; ++e) tmp[q * 4 + e] = f2bf((float)wv[e] * sc);
            }
            #pragma unroll
            for (int e = 0; e < 16; ++e) Bs[srow][scol + e] = tmp[e];
        }
        __syncthreads();
        bf16x8 a[4], b[4];
        #pragma unroll
        for (int i = 0; i < 4; ++i) a[i] = *(const bf16x8*)&As[wm + i * 16 + fr][fk];
        #pragma unroll
        for (int j = 0; j < 4; ++j) b[j] = *(const bf16x8*)&Bs[wn + j * 16 + fr][fk];
        #pragma unroll
        for (int i = 0; i < 4; ++i)
            #pragma unroll
            for (int j = 0; j < 4; ++j)
                acc[i][j] = __builtin_amdgcn_mfma_f32_16x16x32_bf16(a[i], b[j], acc[i][j], 0, 0, 0);
        __syncthreads();
    }
    #pragma unroll
    for (int i = 0; i < 4; ++i) {
        const int row = bm * 128 + wm + i * 16 + fq * 4;
        #pragma unroll
        for (int j = 0; j < 4; ++j) {
            const int col = bn * 128 + wn + j * 16 + fr;
            const float bv = bias[col];
            #pragma unroll
            for (int e = 0; e < 4; ++e)
                out[(size_t)(row + e) * OUT_DIM + col] = acc[i][j][e] + bv;
        }
    }
}

extern "C" void kernel_launch(void* const* d_in, const int* in_sizes, int n_in,
                              void* d_out, int out_size, void* d_ws, size_t ws_size,
                              hipStream_t stream) {
    const float* x      = (const float*)d_in[0];
    const int*   wq     = (const int*)  d_in[1];
    const float* scales = (const float*)d_in[2];
    const float* s      = (const float*)d_in[3];
    const float* bias   = (const float*)d_in[4];
    float* out = (float*)d_out;

    // ws layout (16B-aligned): Aq 8MB | sx 8KB | Bq 43MB | scT 1.4MB
    const size_t off_sx = (size_t)TOKENS * IN_DIM;             // 8388608
    const size_t off_bq = off_sx + 8192;
    const size_t off_sc = off_bq + (size_t)OUT_DIM * IN_DIM;
    const size_t need   = off_sc + (size_t)OUT_DIM * NGROUPS * 4;  // ~54.9MB

    if (ws_size >= need) {
        char*  Aq  = (char*)d_ws;
        float* sxw = (float*)((char*)d_ws + off_sx);
        char*  Bq  = (char*)d_ws + off_bq;
        float* scT = (float*)((char*)d_ws + off_sc);
        prep_a_kernel<<<TOKENS, 256, 0, stream>>>(x, s, Aq, sxw);
        prep_b_kernel<<<OUT_DIM * IN_DIM / 16 / 256, 256, 0, stream>>>(wq, Bq);
        prep_sc_kernel<<<OUT_DIM * NGROUPS / 256, 256, 0, stream>>>(scales, scT);
        awq_gemm_i8<<<768, THREADS, 0, stream>>>(Aq, Bq, scT, sxw, bias, out);
    } else {
        awq_gemm_fb<<<(TOKENS / 128) * (OUT_DIM / 128), 256, 0, stream>>>(x, wq, scales, s, bias, out);
    }
}

// Round 7
// 188.932 us; speedup vs baseline: 2.1679x; 1.4038x over previous
//
#include <hip/hip_runtime.h>
#include <hip/hip_bf16.h>

#define TOKENS  2048
#define IN_DIM  4096
#define OUT_DIM 11008
#define NGROUPS 32

// ---- i8 GEMM geometry: 128x128 tile, BK=128 (= 1 scale group), 16x16x64 MFMA,
//      8 waves (2M x 4N), 2 blocks/CU (64KB LDS). ROUND-0 PROVEN BASE (130us,
//      0 bank conflicts) + ONE change: counted lgkmcnt slab gating so 12/16
//      MFMAs overlap the ds_read drain (was WAITL(0) before any MFMA).
//      launch_bounds (512,2): LDS already caps at 2 blocks/CU; lifts the
//      64-VGPR cap round-0 cleared by only 4 regs (r4 lesson: 2nd arg = blocks/CU).
#define BM 128
#define BN 128
#define BKB 128                // i8 elems (=bytes) per row per K-tile = one quant group
#define THREADS 512
#define NKT   (IN_DIM / BKB)   // 32 K-tiles
#define BUFB  32768            // bytes per LDS buffer (A 16KB + B 16KB)
#define BOFF  16384            // B region offset within buffer

using f32x4  = __attribute__((ext_vector_type(4))) float;
using i32x4  = __attribute__((ext_vector_type(4))) int;
using bf16x8 = __attribute__((ext_vector_type(8))) short;

typedef __attribute__((address_space(3))) char as3c;

static __device__ __forceinline__ short f2bf(float f) {
    union { float f; unsigned u; } v; v.f = f;
    unsigned r = v.u + 0x7FFFu + ((v.u >> 16) & 1u);
    return (short)(r >> 16);
}

static __device__ __forceinline__ int pack4(int a, int b, int c, int d) {
    return (a & 255) | ((b & 255) << 8) | ((c & 255) << 16) | ((d & 255) << 24);
}

#define SB0 __builtin_amdgcn_sched_barrier(0)
#define LDSR(dst, addr)   asm volatile("ds_read_b128 %0, %1" : "=v"(dst) : "v"(addr))
#define WAITL(n) do { asm volatile("s_waitcnt lgkmcnt(" #n ")"); SB0; } while (0)
#define WAITV(n) do { asm volatile("s_waitcnt vmcnt(" #n ")");  SB0; } while (0)

// ---- pass 0a: per-token i8 quant of x/s; sx[row] = max|x/s| / 127 ----
__global__ __launch_bounds__(256) void prep_a_kernel(
    const float* __restrict__ x, const float* __restrict__ s,
    char* __restrict__ Aq, float* __restrict__ sx)
{
    const int row = blockIdx.x, t = threadIdx.x;
    const float* xp = x + (size_t)row * IN_DIM + t * 16;
    const float* sp = s + t * 16;
    f32x4 v[4];
    float m = 0.f;
    #pragma unroll
    for (int q = 0; q < 4; ++q) {
        f32x4 xv = *(const f32x4*)(xp + q * 4);
        f32x4 sv = *(const f32x4*)(sp + q * 4);
        #pragma unroll
        for (int e = 0; e < 4; ++e) {
            v[q][e] = xv[e] / sv[e];
            m = fmaxf(m, fabsf(v[q][e]));
        }
    }
    #pragma unroll
    for (int off = 32; off; off >>= 1) m = fmaxf(m, __shfl_xor(m, off));
    __shared__ float wm[4];
    if ((t & 63) == 0) wm[t >> 6] = m;
    __syncthreads();
    m = fmaxf(fmaxf(wm[0], wm[1]), fmaxf(wm[2], wm[3]));
    m = fmaxf(m, 1e-20f);
    const float inv = 127.0f / m;
    i32x4 pk;
    #pragma unroll
    for (int q = 0; q < 4; ++q)
        pk[q] = pack4((int)rintf(v[q][0] * inv), (int)rintf(v[q][1] * inv),
                      (int)rintf(v[q][2] * inv), (int)rintf(v[q][3] * inv));
    ((i32x4*)(Aq + (size_t)row * IN_DIM))[t] = pk;
    if (t == 0) sx[row] = m * (1.0f / 127.0f);
}

// ---- pass 0b: w_q i32 -> i8 (exact) ----
__global__ __launch_bounds__(256) void prep_b_kernel(
    const int* __restrict__ wq, char* __restrict__ Bq)
{
    const int idx = blockIdx.x * 256 + threadIdx.x;   // 16 elems each
    const int* wp = wq + (size_t)idx * 16;
    i32x4 w0 = *(const i32x4*)wp, w1 = *(const i32x4*)(wp + 4);
    i32x4 w2 = *(const i32x4*)(wp + 8), w3 = *(const i32x4*)(wp + 12);
    i32x4 pk;
    pk[0] = pack4(w0[0], w0[1], w0[2], w0[3]);
    pk[1] = pack4(w1[0], w1[1], w1[2], w1[3]);
    pk[2] = pack4(w2[0], w2[1], w2[2], w2[3]);
    pk[3] = pack4(w3[0], w3[1], w3[2], w3[3]);
    ((i32x4*)Bq)[idx] = pk;
}

// ---- pass 0c: transpose scales [O][G] -> scT [G][O] ----
__global__ __launch_bounds__(256) void prep_sc_kernel(
    const float* __restrict__ scales, float* __restrict__ scT)
{
    const int idx = blockIdx.x * 256 + threadIdx.x;
    const int g = idx / OUT_DIM;
    const int o = idx - g * OUT_DIM;
    scT[idx] = scales[o * NGROUPS + g];
}

// ---- 128x128 i8 GEMM, counted-lgkmcnt slab pipeline, 2 blocks/CU ----
__global__ __launch_bounds__(THREADS, 2) void awq_gemm_i8(
    const char* __restrict__ Aq, const char* __restrict__ Bq,
    const float* __restrict__ scT, const float* __restrict__ sx,
    const float* __restrict__ bias, float* __restrict__ out)
{
    // per-XCD block map (rb&7 -> XCD round-robin)
    const int rb = blockIdx.x;                  // grid 1408 = 8 * 176
    const int bm = (rb >> 3) & 15;              // 0..15
    const int bn = (((rb >> 3) >> 4) << 3) + (rb & 7);  // 0..87
    if (bn >= OUT_DIM / BN) return;             // 32 dead pad blocks

    __shared__ char smem[2 * BUFB];             // 64 KB -> 2 blocks/CU
    as3c* ldsb = (as3c*)smem;
    const unsigned lbase = (unsigned)(size_t)ldsb;

    const int tid  = threadIdx.x;
    const int lane = tid & 63;
    const int w    = tid >> 6;        // wave 0..7
    const int wr   = w >> 2;          // 0..1 (M: 2 x 64)
    const int wc   = w & 3;           // 0..3 (N: 4 x 32)
    const int fr   = lane & 15;
    const int fko  = lane >> 4;       // 0..3

    // fragment LDS read bases (buffer 0); granule slot g holds global granule g^(fr&7)
    const int h7 = fr & 7;
    const unsigned swz0 = (unsigned)(((0 * 4 + fko) ^ h7) * 16);
    const unsigned swz1 = (unsigned)(((1 * 4 + fko) ^ h7) * 16);
    const unsigned aB0 = lbase + (wr * 64 + fr) * 128 + swz0;         // + i*2048 + P*BUFB
    const unsigned aB1 = lbase + (wr * 64 + fr) * 128 + swz1;
    const unsigned bB0 = lbase + BOFF + (wc * 32 + fr) * 128 + swz0;  // + j*2048 + P*BUFB
    const unsigned bB1 = lbase + BOFF + (wc * 32 + fr) * 128 + swz1;

    // staging: thread -> row tid>>3 (0..63) per sweep, granule tid&7 pre-swizzled
    const int srow = tid >> 3;
    const int sg   = ((tid & 7) ^ (srow & 7)) * 16;
    const char* aSrc = Aq + (size_t)(bm * BM + srow) * IN_DIM + sg;
    const char* bSrc = Bq + (size_t)(bn * BN + srow) * IN_DIM + sg;

    // scale source: per-lane column; +16 floats for j=1
    const float* scp = scT + bn * BN + wc * 32 + fr;

#define STG_A(Q, KT, P) __builtin_amdgcn_global_load_lds( \
    (const __attribute__((address_space(1))) void*)(const void*)(aSrc + (size_t)((Q) * 64) * IN_DIM + (KT) * BKB), \
    (__attribute__((address_space(3))) void*)(ldsb + (P) * BUFB + (Q) * 8192 + tid * 16), 16, 0, 0)
#define STG_B(Q, KT, P) __builtin_amdgcn_global_load_lds( \
    (const __attribute__((address_space(1))) void*)(const void*)(bSrc + (size_t)((Q) * 64) * IN_DIM + (KT) * BKB), \
    (__attribute__((address_space(3))) void*)(ldsb + (P) * BUFB + BOFF + (Q) * 8192 + tid * 16), 16, 0, 0)

#define SCV_GLOAD(D0, D1, G) do { \
    asm volatile("global_load_dword %0, %1, off" : "=v"(D0) : "v"(scp + (size_t)(G) * OUT_DIM)); \
    asm volatile("global_load_dword %0, %1, off" : "=v"(D1) : "v"(scp + (size_t)(G) * OUT_DIM + 16)); \
    SB0; } while (0)

// one 16-row M-slab: 4 MFMAs (2 j-cols x 2 k-chunks) + inline dequant into f32 acc
#define MMI(A0, A1, F0, F1) do { \
    i32x4 t0 = __builtin_amdgcn_mfma_i32_16x16x64_i8(A0, b00, (i32x4){0,0,0,0}, 0, 0, 0); \
    t0       = __builtin_amdgcn_mfma_i32_16x16x64_i8(A1, b01, t0, 0, 0, 0); \
    i32x4 t1 = __builtin_amdgcn_mfma_i32_16x16x64_i8(A0, b10, (i32x4){0,0,0,0}, 0, 0, 0); \
    t1       = __builtin_amdgcn_mfma_i32_16x16x64_i8(A1, b11, t1, 0, 0, 0); \
    _Pragma("unroll") \
    for (int e = 0; e < 4; ++e) { \
        F0[e] += (float)t0[e] * c0; \
        F1[e] += (float)t1[e] * c1; \
    } } while (0)

    f32x4 accf[4][2];
    #pragma unroll
    for (int i = 0; i < 4; ++i) {
        accf[i][0] = (f32x4){0.f, 0.f, 0.f, 0.f};
        accf[i][1] = (f32x4){0.f, 0.f, 0.f, 0.f};
    }

    float c0, c1, n0 = 0.f, n1 = 0.f;

    // prologue ledger: S0[4], V0[2], S1[4] -> WAITV(4) retires S0+V0, keeps S1
    STG_A(0, 0, 0); STG_A(1, 0, 0); STG_B(0, 0, 0); STG_B(1, 0, 0);
    SCV_GLOAD(c0, c1, 0);
    STG_A(0, 1, 1); STG_A(1, 1, 1); STG_B(0, 1, 1); STG_B(1, 1, 1);
    WAITV(4);
    __builtin_amdgcn_s_barrier();
    SB0;

    for (int t = 0; t < NKT; ++t) {
        const int P = t & 1;
        const unsigned po = (unsigned)(P * BUFB);
        const bool haveN = (t + 1 < NKT);   // next scale group exists
        const bool haveS = (t + 2 < NKT);   // next-next tile to stage

        i32x4 a0k0, a0k1, a1k0, a1k1, a2k0, a2k1, a3k0, a3k1;
        i32x4 b00, b01, b10, b11;
        // 12 ds_reads of tile t from buf P — B first, then A slab-ordered,
        // so counted lgkmcnt gates each 4-MFMA slab on exactly its inputs.
        LDSR(b00, bB0 + po);        LDSR(b01, bB1 + po);
        LDSR(b10, bB0 + po + 2048); LDSR(b11, bB1 + po + 2048);
        LDSR(a0k0, aB0 + po);          LDSR(a0k1, aB1 + po);
        LDSR(a1k0, aB0 + po + 2048);   LDSR(a1k1, aB1 + po + 2048);
        LDSR(a2k0, aB0 + po + 4096);   LDSR(a2k1, aB1 + po + 4096);
        LDSR(a3k0, aB0 + po + 6144);   LDSR(a3k1, aB1 + po + 6144);

        __builtin_amdgcn_s_setprio(1);
        WAITL(6);   // B(4)+a0(2) retired
        MMI(a0k0, a0k1, accf[0][0], accf[0][1]);
        WAITL(4);   // +a1
        MMI(a1k0, a1k1, accf[1][0], accf[1][1]);
        WAITL(2);   // +a2
        MMI(a2k0, a2k1, accf[2][0], accf[2][1]);
        WAITL(0);   // all reads of buf P done (this wave)
        __builtin_amdgcn_s_setprio(0);
        __builtin_amdgcn_s_barrier();   // all waves' reads complete -> restage OK
        SB0;

        // prefetch next-group scales, then stage tile t+2 into the freed buf P
        if (haveN) SCV_GLOAD(n0, n1, t + 1);
        if (haveS) { STG_A(0, t + 2, P); STG_A(1, t + 2, P);
                     STG_B(0, t + 2, P); STG_B(1, t + 2, P); }
        SB0;

        __builtin_amdgcn_s_setprio(1);
        MMI(a3k0, a3k1, accf[3][0], accf[3][1]);
        __builtin_amdgcn_s_setprio(0);

        // gate: steady state retires S(t+1)+V(t+1), keeps S(t+2)[4]
        if (t < NKT - 2) { WAITV(4); } else { WAITV(0); }
        __builtin_amdgcn_s_barrier();
        SB0;
        if (haveN) { c0 = n0; c1 = n1; }   // V(t+1) retired at the gate
    }

    // ---- epilogue: * sx[row], + bias[col] ----
    #pragma unroll
    for (int i = 0; i < 4; ++i) {
        const int row = bm * BM + wr * 64 + i * 16 + fko * 4;
        const f32x4 sxv = *(const f32x4*)(sx + row);
        #pragma unroll
        for (int j = 0; j < 2; ++j) {
            const int col = bn * BN + wc * 32 + j * 16 + fr;
            const float bv = bias[col];
            #pragma unroll
            for (int e = 0; e < 4; ++e)
                out[(size_t)(row + e) * OUT_DIM + col] = accf[i][j][e] * sxv[e] + bv;
        }
    }

#undef STG_A
#undef STG_B
#undef SCV_GLOAD
#undef MMI
}

// ---- fallback (no workspace): round-1 proven kernel ----
__global__ __launch_bounds__(256) void awq_gemm_fb(
    const float* __restrict__ x, const int* __restrict__ wq,
    const float* __restrict__ scales, const float* __restrict__ s,
    const float* __restrict__ bias, float* __restrict__ out)
{
    __shared__ short As[128][32];
    __shared__ short Bs[128][32];
    const int tid = threadIdx.x, lane = tid & 63, wave = tid >> 6;
    const int nbn = OUT_DIM / 128;
    const int bm = blockIdx.x / nbn, bn = blockIdx.x % nbn;
    const int srow = tid >> 1, scol = (tid & 1) * 16;
    const int wm = (wave >> 1) * 64, wn = (wave & 1) * 64;
    f32x4 acc[4][4];
    #pragma unroll
    for (int i = 0; i < 4; ++i)
        #pragma unroll
        for (int j = 0; j < 4; ++j) acc[i][j] = (f32x4){0.f, 0.f, 0.f, 0.f};
    const float* xrow = x + (size_t)(bm * 128 + srow) * IN_DIM;
    const int* wrow = wq + (size_t)(bn * 128 + srow) * IN_DIM;
    const float* scrow = scales + (size_t)(bn * 128 + srow) * NGROUPS;
    const int fr = lane & 15, fk = (lane >> 4) * 8, fq = lane >> 4;
    for (int kt = 0; kt < IN_DIM / 32; ++kt) {
        const int k0 = kt * 32;
        {
            const float* xp = xrow + k0 + scol;
            const float* sp = s + k0 + scol;
            short tmp[16];
            #pragma unroll
            for (int q = 0; q < 4; ++q) {
                f32x4 xv = *(const f32x4*)(xp + q * 4);
                f32x4 sv = *(const f32x4*)(sp + q * 4);
                #pragma unroll
                for (int e = 0; e < 4; ++e) tmp[q * 4 + e] = f2bf(xv[e] / sv[e]);
            }
            #pragma unroll
            for (int e = 0; e < 16; ++e) As[srow][scol + e] = tmp[e];
        }
        {
            const float sc = scrow[kt >> 2];
            const int* wp = wrow + k0 + scol;
            short tmp[16];
            #pragma unroll
            for (int q = 0; q < 4; ++q) {
                i32x4 wv = *(const i32x4*)(wp + q * 4);
                #pragma unroll
                for (int e = 0; e < 4; ++e) tmp[q * 4 + e] = f2bf((float)wv[e] * sc);
            }
            #pragma unroll
            for (int e = 0; e < 16; ++e) Bs[srow][scol + e] = tmp[e];
        }
        __syncthreads();
        bf16x8 a[4], b[4];
        #pragma unroll
        for (int i = 0; i < 4; ++i) a[i] = *(const bf16x8*)&As[wm + i * 16 + fr][fk];
        #pragma unroll
        for (int j = 0; j < 4; ++j) b[j] = *(const bf16x8*)&Bs[wn + j * 16 + fr][fk];
        #pragma unroll
        for (int i = 0; i < 4; ++i)
            #pragma unroll
            for (int j = 0; j < 4; ++j)
                acc[i][j] = __builtin_amdgcn_mfma_f32_16x16x32_bf16(a[i], b[j], acc[i][j], 0, 0, 0);
        __syncthreads();
    }
    #pragma unroll
    for (int i = 0; i < 4; ++i) {
        const int row = bm * 128 + wm + i * 16 + fq * 4;
        #pragma unroll
        for (int j = 0; j < 4; ++j) {
            const int col = bn * 128 + wn + j * 16 + fr;
            const float bv = bias[col];
            #pragma unroll
            for (int e = 0; e < 4; ++e)
                out[(size_t)(row + e) * OUT_DIM + col] = acc[i][j][e] + bv;
        }
    }
}

extern "C" void kernel_launch(void* const* d_in, const int* in_sizes, int n_in,
                              void* d_out, int out_size, void* d_ws, size_t ws_size,
                              hipStream_t stream) {
    const float* x      = (const float*)d_in[0];
    const int*   wq     = (const int*)  d_in[1];
    const float* scales = (const float*)d_in[2];
    const float* s      = (const float*)d_in[3];
    const float* bias   = (const float*)d_in[4];
    float* out = (float*)d_out;

    // ws layout (16B-aligned): Aq 8MB | sx 8KB | Bq 43MB | scT 1.4MB
    const size_t off_sx = (size_t)TOKENS * IN_DIM;             // 8388608
    const size_t off_bq = off_sx + 8192;
    const size_t off_sc = off_bq + (size_t)OUT_DIM * IN_DIM;
    const size_t need   = off_sc + (size_t)OUT_DIM * NGROUPS * 4;  // ~54.9MB

    if (ws_size >= need) {
        char*  Aq  = (char*)d_ws;
        float* sxw = (float*)((char*)d_ws + off_sx);
        char*  Bq  = (char*)d_ws + off_bq;
        float* scT = (float*)((char*)d_ws + off_sc);
        prep_a_kernel<<<TOKENS, 256, 0, stream>>>(x, s, Aq, sxw);
        prep_b_kernel<<<OUT_DIM * IN_DIM / 16 / 256, 256, 0, stream>>>(wq, Bq);
        prep_sc_kernel<<<OUT_DIM * NGROUPS / 256, 256, 0, stream>>>(scales, scT);
        awq_gemm_i8<<<1408, THREADS, 0, stream>>>(Aq, Bq, scT, sxw, bias, out);
    } else {
        awq_gemm_fb<<<(TOKENS / 128) * (OUT_DIM / 128), 256, 0, stream>>>(x, wq, scales, s, bias, out);
    }
}

// Round 8
// 174.623 us; speedup vs baseline: 2.3456x; 1.0819x over previous
//
#include <hip/hip_runtime.h>
#include <hip/hip_bf16.h>

#define TOKENS  2048
#define IN_DIM  4096
#define OUT_DIM 11008
#define NGROUPS 32

// ---- i8 GEMM geometry: 128x128 tile, BK=128 (= 1 scale group), 1 barrier-pair/K-tile ----
// ROUND-0 PROVEN KERNEL, byte-for-byte (130.3us, FETCH 124MB = XCD-compulsory floor,
// 0 bank conflicts, VGPR 60). Session laws baked in:
//  - full-drain -> restage -> compute phase order is load-bearing for L2 (r7: +76MB FETCH if violated)
//  - 128-B LDS rows + g^(fr&7) granule swizzle = 0 conflicts (64-B rows are +4cy/read, r6)
//  - B must broadcast via LDS, never per-lane global (r5: TA-port, MfmaUtil 14%)
//  - launch_bounds 2nd arg caps VGPR as blocks/CU (r4: arg=4 -> cap 64; this kernel fits in 60)
#define BM 128
#define BN 128
#define BKB 128                // i8 elems (=bytes) per row per K-tile = one quant group
#define THREADS 512
#define NKT   (IN_DIM / BKB)   // 32 K-tiles
#define BUFB  32768            // bytes per LDS buffer (A 16KB + B 16KB)
#define BOFF  16384            // B region offset within buffer

#define PREPA_BLOCKS  TOKENS                         // 2048
#define PREPB_BLOCKS  (OUT_DIM * IN_DIM / 16 / 256)  // 11008
#define PREPSC_BLOCKS (OUT_DIM * NGROUPS / 256)      // 1376
#define PREP_GRID     (PREPA_BLOCKS + PREPB_BLOCKS + PREPSC_BLOCKS)  // 14432

using f32x4  = __attribute__((ext_vector_type(4))) float;
using i32x4  = __attribute__((ext_vector_type(4))) int;
using bf16x8 = __attribute__((ext_vector_type(8))) short;

typedef __attribute__((address_space(3))) char as3c;

static __device__ __forceinline__ short f2bf(float f) {
    union { float f; unsigned u; } v; v.f = f;
    unsigned r = v.u + 0x7FFFu + ((v.u >> 16) & 1u);
    return (short)(r >> 16);
}

static __device__ __forceinline__ int pack4(int a, int b, int c, int d) {
    return (a & 255) | ((b & 255) << 8) | ((c & 255) << 16) | ((d & 255) << 24);
}

#define SB0 __builtin_amdgcn_sched_barrier(0)
#define LDSR(dst, addr)   asm volatile("ds_read_b128 %0, %1" : "=v"(dst) : "v"(addr))
#define WAITL(n) do { asm volatile("s_waitcnt lgkmcnt(" #n ")"); SB0; } while (0)
#define WAITV(n) do { asm volatile("s_waitcnt vmcnt(" #n ")");  SB0; } while (0)

// ---- fused prep: one launch does all three independent passes ----
// blocks [0, 2048)              : per-token i8 quant of x/s; sx[row] = max|x/s|/127
// blocks [2048, 2048+11008)     : w_q i32 -> i8 (exact)
// blocks [2048+11008, 14432)    : transpose scales [O][G] -> scT [G][O]
__global__ __launch_bounds__(256) void prep_fused(
    const float* __restrict__ x, const int* __restrict__ wq,
    const float* __restrict__ scales, const float* __restrict__ s,
    char* __restrict__ Aq, float* __restrict__ sx,
    char* __restrict__ Bq, float* __restrict__ scT)
{
    __shared__ float wm[4];
    const int bid = blockIdx.x, t = threadIdx.x;

    if (bid < PREPA_BLOCKS) {
        // ---- pass A: per-token i8 quant ----
        const int row = bid;
        const float* xp = x + (size_t)row * IN_DIM + t * 16;
        const float* sp = s + t * 16;
        f32x4 v[4];
        float m = 0.f;
        #pragma unroll
        for (int q = 0; q < 4; ++q) {
            f32x4 xv = *(const f32x4*)(xp + q * 4);
            f32x4 sv = *(const f32x4*)(sp + q * 4);
            #pragma unroll
            for (int e = 0; e < 4; ++e) {
                v[q][e] = xv[e] / sv[e];
                m = fmaxf(m, fabsf(v[q][e]));
            }
        }
        #pragma unroll
        for (int off = 32; off; off >>= 1) m = fmaxf(m, __shfl_xor(m, off));
        if ((t & 63) == 0) wm[t >> 6] = m;
        __syncthreads();
        m = fmaxf(fmaxf(wm[0], wm[1]), fmaxf(wm[2], wm[3]));
        m = fmaxf(m, 1e-20f);
        const float inv = 127.0f / m;
        i32x4 pk;
        #pragma unroll
        for (int q = 0; q < 4; ++q)
            pk[q] = pack4((int)rintf(v[q][0] * inv), (int)rintf(v[q][1] * inv),
                          (int)rintf(v[q][2] * inv), (int)rintf(v[q][3] * inv));
        ((i32x4*)(Aq + (size_t)row * IN_DIM))[t] = pk;
        if (t == 0) sx[row] = m * (1.0f / 127.0f);
    } else if (bid < PREPA_BLOCKS + PREPB_BLOCKS) {
        // ---- pass B: w_q i32 -> i8 ----
        const int idx = (bid - PREPA_BLOCKS) * 256 + t;   // 16 elems each
        const int* wp = wq + (size_t)idx * 16;
        i32x4 w0 = *(const i32x4*)wp, w1 = *(const i32x4*)(wp + 4);
        i32x4 w2 = *(const i32x4*)(wp + 8), w3 = *(const i32x4*)(wp + 12);
        i32x4 pk;
        pk[0] = pack4(w0[0], w0[1], w0[2], w0[3]);
        pk[1] = pack4(w1[0], w1[1], w1[2], w1[3]);
        pk[2] = pack4(w2[0], w2[1], w2[2], w2[3]);
        pk[3] = pack4(w3[0], w3[1], w3[2], w3[3]);
        ((i32x4*)Bq)[idx] = pk;
    } else {
        // ---- pass SC: scales [O][G] -> scT [G][O] ----
        const int idx = (bid - PREPA_BLOCKS - PREPB_BLOCKS) * 256 + t;
        const int g = idx / OUT_DIM;
        const int o = idx - g * OUT_DIM;
        scT[idx] = scales[o * NGROUPS + g];
    }
}

// ---- 128x128 i8 GEMM, one barrier-pair per K-tile, 2 blocks/CU ----
__global__ __launch_bounds__(THREADS, 4) void awq_gemm_i8(
    const char* __restrict__ Aq, const char* __restrict__ Bq,
    const float* __restrict__ scT, const float* __restrict__ sx,
    const float* __restrict__ bias, float* __restrict__ out)
{
    // per-XCD block map (rb&7 -> XCD round-robin): concurrent per-XCD window
    // = many bm x few bn -> B K-window L2-resident.
    const int rb = blockIdx.x;                  // grid 1408 = 8 * 176
    const int bm = (rb >> 3) & 15;              // 0..15
    const int bn = (((rb >> 3) >> 4) << 3) + (rb & 7);  // 0..87
    if (bn >= OUT_DIM / BN) return;             // 32 dead pad blocks

    __shared__ char smem[2 * BUFB];             // 64 KB -> 2 blocks/CU
    as3c* ldsb = (as3c*)smem;
    const unsigned lbase = (unsigned)(size_t)ldsb;

    const int tid  = threadIdx.x;
    const int lane = tid & 63;
    const int w    = tid >> 6;        // wave 0..7
    const int wr   = w >> 2;          // 0..1 (M: 2 x 64)
    const int wc   = w & 3;           // 0..3 (N: 4 x 32)
    const int fr   = lane & 15;
    const int fko  = lane >> 4;       // 0..3

    // fragment LDS read bases (buffer 0); granule slot g holds global granule g^(r&7)
    const int h7 = fr & 7;
    const unsigned swz0 = (unsigned)(((0 * 4 + fko) ^ h7) * 16);
    const unsigned swz1 = (unsigned)(((1 * 4 + fko) ^ h7) * 16);
    const unsigned aB0 = lbase + (wr * 64 + fr) * 128 + swz0;         // + i*2048 + P*BUFB
    const unsigned aB1 = lbase + (wr * 64 + fr) * 128 + swz1;
    const unsigned bB0 = lbase + BOFF + (wc * 32 + fr) * 128 + swz0;  // + j*2048 + P*BUFB
    const unsigned bB1 = lbase + BOFF + (wc * 32 + fr) * 128 + swz1;

    // staging: thread -> row tid>>3 (0..63) per sweep, granule tid&7 pre-swizzled
    const int srow = tid >> 3;
    const int sg   = ((tid & 7) ^ (srow & 7)) * 16;
    const char* aSrc = Aq + (size_t)(bm * BM + srow) * IN_DIM + sg;
    const char* bSrc = Bq + (size_t)(bn * BN + srow) * IN_DIM + sg;

    // scale source: per-lane column; +16 floats for j=1
    const float* scp = scT + bn * BN + wc * 32 + fr;

#define STG_A(Q, KT, P) __builtin_amdgcn_global_load_lds( \
    (const __attribute__((address_space(1))) void*)(const void*)(aSrc + (size_t)((Q) * 64) * IN_DIM + (KT) * BKB), \
    (__attribute__((address_space(3))) void*)(ldsb + (P) * BUFB + (Q) * 8192 + tid * 16), 16, 0, 0)
#define STG_B(Q, KT, P) __builtin_amdgcn_global_load_lds( \
    (const __attribute__((address_space(1))) void*)(const void*)(bSrc + (size_t)((Q) * 64) * IN_DIM + (KT) * BKB), \
    (__attribute__((address_space(3))) void*)(ldsb + (P) * BUFB + BOFF + (Q) * 8192 + tid * 16), 16, 0, 0)

#define SCV_GLOAD(D0, D1, G) do { \
    asm volatile("global_load_dword %0, %1, off" : "=v"(D0) : "v"(scp + (size_t)(G) * OUT_DIM)); \
    asm volatile("global_load_dword %0, %1, off" : "=v"(D1) : "v"(scp + (size_t)(G) * OUT_DIM + 16)); \
    SB0; } while (0)

    f32x4 accf[4][2];
    #pragma unroll
    for (int i = 0; i < 4; ++i) {
        accf[i][0] = (f32x4){0.f, 0.f, 0.f, 0.f};
        accf[i][1] = (f32x4){0.f, 0.f, 0.f, 0.f};
    }

    float c0, c1, n0 = 0.f, n1 = 0.f;

    // prologue ledger: S0[4], V0[2], S1[4] -> WAITV(4) retires S0+V0, keeps S1
    STG_A(0, 0, 0); STG_A(1, 0, 0); STG_B(0, 0, 0); STG_B(1, 0, 0);
    SCV_GLOAD(c0, c1, 0);
    STG_A(0, 1, 1); STG_A(1, 1, 1); STG_B(0, 1, 1); STG_B(1, 1, 1);
    WAITV(4);
    __builtin_amdgcn_s_barrier();
    SB0;

    for (int t = 0; t < NKT; ++t) {
        const int P = t & 1;
        const unsigned po = (unsigned)(P * BUFB);
        const bool haveN = (t + 1 < NKT);   // next scale group exists
        const bool haveS = (t + 2 < NKT);   // next-next tile to stage

        i32x4 a[4][2], b[2][2];
        // 12 ds_reads of tile t from buf P
        LDSR(b[0][0], bB0 + po);        LDSR(b[0][1], bB1 + po);
        LDSR(b[1][0], bB0 + po + 2048); LDSR(b[1][1], bB1 + po + 2048);
        #pragma unroll
        for (int i = 0; i < 4; ++i) {
            LDSR(a[i][0], aB0 + po + i * 2048);
            LDSR(a[i][1], aB1 + po + i * 2048);
        }
        WAITL(0);                       // this wave's reads complete (+ SB0)
        __builtin_amdgcn_s_barrier();   // all waves' reads complete
        SB0;                            // nothing may hoist above the barrier

        // prefetch next-group scales, then stage tile t+2 into the freed buf P
        if (haveN) SCV_GLOAD(n0, n1, t + 1);
        if (haveS) { STG_A(0, t + 2, P); STG_A(1, t + 2, P);
                     STG_B(0, t + 2, P); STG_B(1, t + 2, P); }

        __builtin_amdgcn_s_setprio(1);
        #pragma unroll
        for (int i = 0; i < 4; ++i) {
            i32x4 t0 = __builtin_amdgcn_mfma_i32_16x16x64_i8(a[i][0], b[0][0], (i32x4){0,0,0,0}, 0, 0, 0);
            t0       = __builtin_amdgcn_mfma_i32_16x16x64_i8(a[i][1], b[0][1], t0, 0, 0, 0);
            i32x4 t1 = __builtin_amdgcn_mfma_i32_16x16x64_i8(a[i][0], b[1][0], (i32x4){0,0,0,0}, 0, 0, 0);
            t1       = __builtin_amdgcn_mfma_i32_16x16x64_i8(a[i][1], b[1][1], t1, 0, 0, 0);
            #pragma unroll
            for (int e = 0; e < 4; ++e) {
                accf[i][0][e] += (float)t0[e] * c0;
                accf[i][1][e] += (float)t1[e] * c1;
            }
        }
        __builtin_amdgcn_s_setprio(0);

        // gate: steady state retires S(t+1)+V(t+1), keeps S(t+2)[4]
        if (t < NKT - 2) { WAITV(4); } else { WAITV(0); }
        __builtin_amdgcn_s_barrier();
        SB0;
        if (haveN) { c0 = n0; c1 = n1; }   // V(t+1) retired at the gate
    }

    // ---- epilogue: * sx[row], + bias[col] ----
    #pragma unroll
    for (int i = 0; i < 4; ++i) {
        const int row = bm * BM + wr * 64 + i * 16 + fko * 4;
        const f32x4 sxv = *(const f32x4*)(sx + row);
        #pragma unroll
        for (int j = 0; j < 2; ++j) {
            const int col = bn * BN + wc * 32 + j * 16 + fr;
            const float bv = bias[col];
            #pragma unroll
            for (int e = 0; e < 4; ++e)
                out[(size_t)(row + e) * OUT_DIM + col] = accf[i][j][e] * sxv[e] + bv;
        }
    }

#undef STG_A
#undef STG_B
#undef SCV_GLOAD
}

// ---- fallback (no workspace): round-1 proven kernel ----
__global__ __launch_bounds__(256) void awq_gemm_fb(
    const float* __restrict__ x, const int* __restrict__ wq,
    const float* __restrict__ scales, const float* __restrict__ s,
    const float* __restrict__ bias, float* __restrict__ out)
{
    __shared__ short As[128][32];
    __shared__ short Bs[128][32];
    const int tid = threadIdx.x, lane = tid & 63, wave = tid >> 6;
    const int nbn = OUT_DIM / 128;
    const int bm = blockIdx.x / nbn, bn = blockIdx.x % nbn;
    const int srow = tid >> 1, scol = (tid & 1) * 16;
    const int wm = (wave >> 1) * 64, wn = (wave & 1) * 64;
    f32x4 acc[4][4];
    #pragma unroll
    for (int i = 0; i < 4; ++i)
        #pragma unroll
        for (int j = 0; j < 4; ++j) acc[i][j] = (f32x4){0.f, 0.f, 0.f, 0.f};
    const float* xrow = x + (size_t)(bm * 128 + srow) * IN_DIM;
    const int* wrow = wq + (size_t)(bn * 128 + srow) * IN_DIM;
    const float* scrow = scales + (size_t)(bn * 128 + srow) * NGROUPS;
    const int fr = lane & 15, fk = (lane >> 4) * 8, fq = lane >> 4;
    for (int kt = 0; kt < IN_DIM / 32; ++kt) {
        const int k0 = kt * 32;
        {
            const float* xp = xrow + k0 + scol;
            const float* sp = s + k0 + scol;
            short tmp[16];
            #pragma unroll
            for (int q = 0; q < 4; ++q) {
                f32x4 xv = *(const f32x4*)(xp + q * 4);
                f32x4 sv = *(const f32x4*)(sp + q * 4);
                #pragma unroll
                for (int e = 0; e < 4; ++e) tmp[q * 4 + e] = f2bf(xv[e] / sv[e]);
            }
            #pragma unroll
            for (int e = 0; e < 16; ++e) As[srow][scol + e] = tmp[e];
        }
        {
            const float sc = scrow[kt >> 2];
            const int* wp = wrow + k0 + scol;
            short tmp[16];
            #pragma unroll
            for (int q = 0; q < 4; ++q) {
                i32x4 wv = *(const i32x4*)(wp + q * 4);
                #pragma unroll
                for (int e = 0; e < 4; ++e) tmp[q * 4 + e] = f2bf((float)wv[e] * sc);
            }
            #pragma unroll
            for (int e = 0; e < 16; ++e) Bs[srow][scol + e] = tmp[e];
        }
        __syncthreads();
        bf16x8 a[4], b[4];
        #pragma unroll
        for (int i = 0; i < 4; ++i) a[i] = *(const bf16x8*)&As[wm + i * 16 + fr][fk];
        #pragma unroll
        for (int j = 0; j < 4; ++j) b[j] = *(const bf16x8*)&Bs[wn + j * 16 + fr][fk];
        #pragma unroll
        for (int i = 0; i < 4; ++i)
            #pragma unroll
            for (int j = 0; j < 4; ++j)
                acc[i][j] = __builtin_amdgcn_mfma_f32_16x16x32_bf16(a[i], b[j], acc[i][j], 0, 0, 0);
        __syncthreads();
    }
    #pragma unroll
    for (int i = 0; i < 4; ++i) {
        const int row = bm * 128 + wm + i * 16 + fq * 4;
        #pragma unroll
        for (int j = 0; j < 4; ++j) {
            const int col = bn * 128 + wn + j * 16 + fr;
            const float bv = bias[col];
            #pragma unroll
            for (int e = 0; e < 4; ++e)
                out[(size_t)(row + e) * OUT_DIM + col] = acc[i][j][e] + bv;
        }
    }
}

extern "C" void kernel_launch(void* const* d_in, const int* in_sizes, int n_in,
                              void* d_out, int out_size, void* d_ws, size_t ws_size,
                              hipStream_t stream) {
    const float* x      = (const float*)d_in[0];
    const int*   wq     = (const int*)  d_in[1];
    const float* scales = (const float*)d_in[2];
    const float* s      = (const float*)d_in[3];
    const float* bias   = (const float*)d_in[4];
    float* out = (float*)d_out;

    // ws layout (16B-aligned): Aq 8MB | sx 8KB | Bq 43MB | scT 1.4MB
    const size_t off_sx = (size_t)TOKENS * IN_DIM;             // 8388608
    const size_t off_bq = off_sx + 8192;
    const size_t off_sc = off_bq + (size_t)OUT_DIM * IN_DIM;
    const size_t need   = off_sc + (size_t)OUT_DIM * NGROUPS * 4;  // ~54.9MB

    if (ws_size >= need) {
        char*  Aq  = (char*)d_ws;
        float* sxw = (float*)((char*)d_ws + off_sx);
        char*  Bq  = (char*)d_ws + off_bq;
        float* scT = (float*)((char*)d_ws + off_sc);
        prep_fused<<<PREP_GRID, 256, 0, stream>>>(x, wq, scales, s, Aq, sxw, Bq, scT);
        awq_gemm_i8<<<1408, THREADS, 0, stream>>>(Aq, Bq, scT, sxw, bias, out);
    } else {
        awq_gemm_fb<<<(TOKENS / 128) * (OUT_DIM / 128), 256, 0, stream>>>(x, wq, scales, s, bias, out);
    }
}

// Round 9
// 173.747 us; speedup vs baseline: 2.3574x; 1.0050x over previous
//
#include <hip/hip_runtime.h>
#include <hip/hip_bf16.h>

#define TOKENS  2048
#define IN_DIM  4096
#define OUT_DIM 11008
#define NGROUPS 32

// ---- i8 GEMM geometry: 128x128 tile, BK=128 (= 1 scale group), 16x16x64 MFMA,
//      4 waves of 64x64 (2M x 2N), SINGLE 32KB LDS buffer, 3 blocks/CU.
//      Square per-wave tiles cut LDS reads 96->64 KB/block-tile (the measured
//      bottleneck); 256-thr blocks @ (256,3) give a 170-VGPR cap that fits the
//      128-reg frag+acc live set (the wall that killed r3-r5); 3-deep block
//      co-scheduling covers the drain (the wall that killed r1/r2).
//      LDS row format + swizzle byte-identical to the proven r0 kernel
//      (128B rows, slot g holds granule g^(row&7): 0 conflicts measured).
//      Restage is immediately post-drain (r7 law); WAITV(0)+barrier ledger.
#define BM 128
#define BN 128
#define BKB 128                // i8 elems (=bytes) per row per K-tile = one quant group
#define THREADS 256
#define NKT   (IN_DIM / BKB)   // 32 K-tiles
#define BUFB  32768            // single LDS buffer (A 16KB + B 16KB)
#define BOFF  16384            // B region offset within buffer

#define PREPA_BLOCKS  TOKENS                         // 2048
#define PREPB_BLOCKS  (OUT_DIM * IN_DIM / 16 / 256)  // 11008
#define PREPSC_BLOCKS (OUT_DIM * NGROUPS / 256)      // 1376
#define PREP_GRID     (PREPA_BLOCKS + PREPB_BLOCKS + PREPSC_BLOCKS)  // 14432

using f32x4  = __attribute__((ext_vector_type(4))) float;
using i32x4  = __attribute__((ext_vector_type(4))) int;
using bf16x8 = __attribute__((ext_vector_type(8))) short;

typedef __attribute__((address_space(3))) char as3c;

static __device__ __forceinline__ short f2bf(float f) {
    union { float f; unsigned u; } v; v.f = f;
    unsigned r = v.u + 0x7FFFu + ((v.u >> 16) & 1u);
    return (short)(r >> 16);
}

static __device__ __forceinline__ int pack4(int a, int b, int c, int d) {
    return (a & 255) | ((b & 255) << 8) | ((c & 255) << 16) | ((d & 255) << 24);
}

#define SB0 __builtin_amdgcn_sched_barrier(0)
#define LDSR(dst, addr)   asm volatile("ds_read_b128 %0, %1" : "=v"(dst) : "v"(addr))
#define WAITL(n) do { asm volatile("s_waitcnt lgkmcnt(" #n ")"); SB0; } while (0)
#define WAITV(n) do { asm volatile("s_waitcnt vmcnt(" #n ")");  SB0; } while (0)

// ---- fused prep: one launch does all three independent passes (r8, proven) ----
__global__ __launch_bounds__(256) void prep_fused(
    const float* __restrict__ x, const int* __restrict__ wq,
    const float* __restrict__ scales, const float* __restrict__ s,
    char* __restrict__ Aq, float* __restrict__ sx,
    char* __restrict__ Bq, float* __restrict__ scT)
{
    __shared__ float wm[4];
    const int bid = blockIdx.x, t = threadIdx.x;

    if (bid < PREPA_BLOCKS) {
        const int row = bid;
        const float* xp = x + (size_t)row * IN_DIM + t * 16;
        const float* sp = s + t * 16;
        f32x4 v[4];
        float m = 0.f;
        #pragma unroll
        for (int q = 0; q < 4; ++q) {
            f32x4 xv = *(const f32x4*)(xp + q * 4);
            f32x4 sv = *(const f32x4*)(sp + q * 4);
            #pragma unroll
            for (int e = 0; e < 4; ++e) {
                v[q][e] = xv[e] / sv[e];
                m = fmaxf(m, fabsf(v[q][e]));
            }
        }
        #pragma unroll
        for (int off = 32; off; off >>= 1) m = fmaxf(m, __shfl_xor(m, off));
        if ((t & 63) == 0) wm[t >> 6] = m;
        __syncthreads();
        m = fmaxf(fmaxf(wm[0], wm[1]), fmaxf(wm[2], wm[3]));
        m = fmaxf(m, 1e-20f);
        const float inv = 127.0f / m;
        i32x4 pk;
        #pragma unroll
        for (int q = 0; q < 4; ++q)
            pk[q] = pack4((int)rintf(v[q][0] * inv), (int)rintf(v[q][1] * inv),
                          (int)rintf(v[q][2] * inv), (int)rintf(v[q][3] * inv));
        ((i32x4*)(Aq + (size_t)row * IN_DIM))[t] = pk;
        if (t == 0) sx[row] = m * (1.0f / 127.0f);
    } else if (bid < PREPA_BLOCKS + PREPB_BLOCKS) {
        const int idx = (bid - PREPA_BLOCKS) * 256 + t;   // 16 elems each
        const int* wp = wq + (size_t)idx * 16;
        i32x4 w0 = *(const i32x4*)wp, w1 = *(const i32x4*)(wp + 4);
        i32x4 w2 = *(const i32x4*)(wp + 8), w3 = *(const i32x4*)(wp + 12);
        i32x4 pk;
        pk[0] = pack4(w0[0], w0[1], w0[2], w0[3]);
        pk[1] = pack4(w1[0], w1[1], w1[2], w1[3]);
        pk[2] = pack4(w2[0], w2[1], w2[2], w2[3]);
        pk[3] = pack4(w3[0], w3[1], w3[2], w3[3]);
        ((i32x4*)Bq)[idx] = pk;
    } else {
        const int idx = (bid - PREPA_BLOCKS - PREPB_BLOCKS) * 256 + t;
        const int g = idx / OUT_DIM;
        const int o = idx - g * OUT_DIM;
        scT[idx] = scales[o * NGROUPS + g];
    }
}

// ---- 128x128 i8 GEMM, 4 waves of 64x64, single-buffer, 3 blocks/CU ----
__global__ __launch_bounds__(THREADS, 3) void awq_gemm_i8(
    const char* __restrict__ Aq, const char* __restrict__ Bq,
    const float* __restrict__ scT, const float* __restrict__ sx,
    const float* __restrict__ bias, float* __restrict__ out)
{
    // per-XCD block map (rb&7 -> XCD round-robin), same as r0
    const int rb = blockIdx.x;                  // grid 1408 = 8 * 176
    const int bm = (rb >> 3) & 15;              // 0..15
    const int bn = (((rb >> 3) >> 4) << 3) + (rb & 7);  // 0..87
    if (bn >= OUT_DIM / BN) return;             // 32 dead pad blocks

    __shared__ char smem[BUFB];                 // 32 KB single buffer
    as3c* ldsb = (as3c*)smem;
    const unsigned lbase = (unsigned)(size_t)ldsb;

    const int tid  = threadIdx.x;
    const int lane = tid & 63;
    const int w    = tid >> 6;        // wave 0..3
    const int wr   = w >> 1;          // 0..1 (M: 2 x 64)
    const int wc   = w & 1;           // 0..1 (N: 2 x 64)
    const int fr   = lane & 15;
    const int fko  = lane >> 4;       // 0..3

    // fragment LDS read bases; slot g holds global granule g^(fr&7)  [r0-proven]
    const int h7 = fr & 7;
    const unsigned swz0 = (unsigned)(((0 * 4 + fko) ^ h7) * 16);
    const unsigned swz1 = (unsigned)(((1 * 4 + fko) ^ h7) * 16);
    const unsigned aB0 = lbase + (wr * 64 + fr) * 128 + swz0;         // + i*2048
    const unsigned aB1 = lbase + (wr * 64 + fr) * 128 + swz1;
    const unsigned bB0 = lbase + BOFF + (wc * 64 + fr) * 128 + swz0;  // + j*2048
    const unsigned bB1 = lbase + BOFF + (wc * 64 + fr) * 128 + swz1;

    // staging: thread -> row tid>>3 (0..31) per sweep, granule tid&7 pre-swizzled
    const int srow = tid >> 3;
    const int sg   = ((tid & 7) ^ (srow & 7)) * 16;
    const char* aSrc = Aq + (size_t)(bm * BM + srow) * IN_DIM + sg;
    const char* bSrc = Bq + (size_t)(bn * BN + srow) * IN_DIM + sg;

    // scales: lane's 4 columns are wc*64 + j*16 + fr, j=0..3 (stride 64 B)
    const float* scp = scT + bn * BN + wc * 64 + fr;

#define STG_A(Q, KT) __builtin_amdgcn_global_load_lds( \
    (const __attribute__((address_space(1))) void*)(const void*)(aSrc + (size_t)((Q) * 32) * IN_DIM + (KT) * BKB), \
    (__attribute__((address_space(3))) void*)(ldsb + (Q) * 4096 + tid * 16), 16, 0, 0)
#define STG_B(Q, KT) __builtin_amdgcn_global_load_lds( \
    (const __attribute__((address_space(1))) void*)(const void*)(bSrc + (size_t)((Q) * 32) * IN_DIM + (KT) * BKB), \
    (__attribute__((address_space(3))) void*)(ldsb + BOFF + (Q) * 4096 + tid * 16), 16, 0, 0)
#define STG_TILE(KT) do { \
    STG_A(0, KT); STG_A(1, KT); STG_A(2, KT); STG_A(3, KT); \
    STG_B(0, KT); STG_B(1, KT); STG_B(2, KT); STG_B(3, KT); \
    SB0; } while (0)

#define SCV4(D0, D1, D2, D3, G) do { \
    asm volatile("global_load_dword %0, %1, off"            : "=v"(D0) : "v"(scp + (size_t)(G) * OUT_DIM)); \
    asm volatile("global_load_dword %0, %1, off offset:64"  : "=v"(D1) : "v"(scp + (size_t)(G) * OUT_DIM)); \
    asm volatile("global_load_dword %0, %1, off offset:128" : "=v"(D2) : "v"(scp + (size_t)(G) * OUT_DIM)); \
    asm volatile("global_load_dword %0, %1, off offset:192" : "=v"(D3) : "v"(scp + (size_t)(G) * OUT_DIM)); \
    SB0; } while (0)

// column j: 4 slabs x (2 chained MFMAs) + dequant into f32 master acc
#define QUADJ(J, CJ) do { \
    _Pragma("unroll") \
    for (int i = 0; i < 4; ++i) { \
        i32x4 tq = __builtin_amdgcn_mfma_i32_16x16x64_i8(a[i][0], b[J][0], (i32x4){0,0,0,0}, 0, 0, 0); \
        tq       = __builtin_amdgcn_mfma_i32_16x16x64_i8(a[i][1], b[J][1], tq, 0, 0, 0); \
        _Pragma("unroll") \
        for (int e = 0; e < 4; ++e) accf[i][J][e] += (float)tq[e] * (CJ); \
    } } while (0)

    f32x4 accf[4][4];
    #pragma unroll
    for (int i = 0; i < 4; ++i)
        #pragma unroll
        for (int j = 0; j < 4; ++j) accf[i][j] = (f32x4){0.f, 0.f, 0.f, 0.f};

    float c0, c1, c2, c3, n0 = 0.f, n1 = 0.f, n2 = 0.f, n3 = 0.f;

    // prologue: stage tile 0 + group-0 scales, full drain
    STG_TILE(0);
    SCV4(c0, c1, c2, c3, 0);
    WAITV(0);
    __builtin_amdgcn_s_barrier();
    SB0;

    for (int t = 0; t < NKT; ++t) {
        const bool haveN = (t + 1 < NKT);

        i32x4 a[4][2], b[4][2];
        // 16 ds_reads of tile t (64 KB/block: A x2, B x2 re-read — square waves)
        #pragma unroll
        for (int i = 0; i < 4; ++i) {
            LDSR(a[i][0], aB0 + i * 2048);
            LDSR(a[i][1], aB1 + i * 2048);
        }
        #pragma unroll
        for (int j = 0; j < 4; ++j) {
            LDSR(b[j][0], bB0 + j * 2048);
            LDSR(b[j][1], bB1 + j * 2048);
        }
        WAITL(0);                       // this wave's frags in regs
        __builtin_amdgcn_s_barrier();   // all waves done reading -> buffer free
        SB0;                            // nothing may hoist above the barrier

        // restage IMMEDIATELY post-drain (r7 L2 law), + next-group scales
        if (haveN) {
            SCV4(n0, n1, n2, n3, t + 1);
            STG_TILE(t + 1);
        }
        SB0;

        __builtin_amdgcn_s_setprio(1);
        QUADJ(0, c0); QUADJ(1, c1); QUADJ(2, c2); QUADJ(3, c3);
        __builtin_amdgcn_s_setprio(0);

        WAITV(0);                       // tile t+1 DMA + scales landed
        __builtin_amdgcn_s_barrier();
        SB0;
        if (haveN) { c0 = n0; c1 = n1; c2 = n2; c3 = n3; }
    }

    // ---- epilogue: * sx[row], + bias[col] ----
    #pragma unroll
    for (int i = 0; i < 4; ++i) {
        const int row = bm * BM + wr * 64 + i * 16 + fko * 4;
        const f32x4 sxv = *(const f32x4*)(sx + row);
        #pragma unroll
        for (int j = 0; j < 4; ++j) {
            const int col = bn * BN + wc * 64 + j * 16 + fr;
            const float bv = bias[col];
            #pragma unroll
            for (int e = 0; e < 4; ++e)
                out[(size_t)(row + e) * OUT_DIM + col] = accf[i][j][e] * sxv[e] + bv;
        }
    }

#undef STG_A
#undef STG_B
#undef STG_TILE
#undef SCV4
#undef QUADJ
}

// ---- fallback (no workspace): round-1 proven kernel ----
__global__ __launch_bounds__(256) void awq_gemm_fb(
    const float* __restrict__ x, const int* __restrict__ wq,
    const float* __restrict__ scales, const float* __restrict__ s,
    const float* __restrict__ bias, float* __restrict__ out)
{
    __shared__ short As[128][32];
    __shared__ short Bs[128][32];
    const int tid = threadIdx.x, lane = tid & 63, wave = tid >> 6;
    const int nbn = OUT_DIM / 128;
    const int bm = blockIdx.x / nbn, bn = blockIdx.x % nbn;
    const int srow = tid >> 1, scol = (tid & 1) * 16;
    const int wm = (wave >> 1) * 64, wn = (wave & 1) * 64;
    f32x4 acc[4][4];
    #pragma unroll
    for (int i = 0; i < 4; ++i)
        #pragma unroll
        for (int j = 0; j < 4; ++j) acc[i][j] = (f32x4){0.f, 0.f, 0.f, 0.f};
    const float* xrow = x + (size_t)(bm * 128 + srow) * IN_DIM;
    const int* wrow = wq + (size_t)(bn * 128 + srow) * IN_DIM;
    const float* scrow = scales + (size_t)(bn * 128 + srow) * NGROUPS;
    const int fr = lane & 15, fk = (lane >> 4) * 8, fq = lane >> 4;
    for (int kt = 0; kt < IN_DIM / 32; ++kt) {
        const int k0 = kt * 32;
        {
            const float* xp = xrow + k0 + scol;
            const float* sp = s + k0 + scol;
            short tmp[16];
            #pragma unroll
            for (int q = 0; q < 4; ++q) {
                f32x4 xv = *(const f32x4*)(xp + q * 4);
                f32x4 sv = *(const f32x4*)(sp + q * 4);
                #pragma unroll
                for (int e = 0; e < 4; ++e) tmp[q * 4 + e] = f2bf(xv[e] / sv[e]);
            }
            #pragma unroll
            for (int e = 0; e < 16; ++e) As[srow][scol + e] = tmp[e];
        }
        {
            const float sc = scrow[kt >> 2];
            const int* wp = wrow + k0 + scol;
            short tmp[16];
            #pragma unroll
            for (int q = 0; q < 4; ++q) {
                i32x4 wv = *(const i32x4*)(wp + q * 4);
                #pragma unroll
                for (int e = 0; e < 4; ++e) tmp[q * 4 + e] = f2bf((float)wv[e] * sc);
            }
            #pragma unroll
            for (int e = 0; e < 16; ++e) Bs[srow][scol + e] = tmp[e];
        }
        __syncthreads();
        bf16x8 a[4], b[4];
        #pragma unroll
        for (int i = 0; i < 4; ++i) a[i] = *(const bf16x8*)&As[wm + i * 16 + fr][fk];
        #pragma unroll
        for (int j = 0; j < 4; ++j) b[j] = *(const bf16x8*)&Bs[wn + j * 16 + fr][fk];
        #pragma unroll
        for (int i = 0; i < 4; ++i)
            #pragma unroll
            for (int j = 0; j < 4; ++j)
                acc[i][j] = __builtin_amdgcn_mfma_f32_16x16x32_bf16(a[i], b[j], acc[i][j], 0, 0, 0);
        __syncthreads();
    }
    #pragma unroll
    for (int i = 0; i < 4; ++i) {
        const int row = bm * 128 + wm + i * 16 + fq * 4;
        #pragma unroll
        for (int j = 0; j < 4; ++j) {
            const int col = bn * 128 + wn + j * 16 + fr;
            const float bv = bias[col];
            #pragma unroll
            for (int e = 0; e < 4; ++e)
                out[(size_t)(row + e) * OUT_DIM + col] = acc[i][j][e] + bv;
        }
    }
}

extern "C" void kernel_launch(void* const* d_in, const int* in_sizes, int n_in,
                              void* d_out, int out_size, void* d_ws, size_t ws_size,
                              hipStream_t stream) {
    const float* x      = (const float*)d_in[0];
    const int*   wq     = (const int*)  d_in[1];
    const float* scales = (const float*)d_in[2];
    const float* s      = (const float*)d_in[3];
    const float* bias   = (const float*)d_in[4];
    float* out = (float*)d_out;

    // ws layout (16B-aligned): Aq 8MB | sx 8KB | Bq 43MB | scT 1.4MB
    const size_t off_sx = (size_t)TOKENS * IN_DIM;             // 8388608
    const size_t off_bq = off_sx + 8192;
    const size_t off_sc = off_bq + (size_t)OUT_DIM * IN_DIM;
    const size_t need   = off_sc + (size_t)OUT_DIM * NGROUPS * 4;  // ~54.9MB

    if (ws_size >= need) {
        char*  Aq  = (char*)d_ws;
        float* sxw = (float*)((char*)d_ws + off_sx);
        char*  Bq  = (char*)d_ws + off_bq;
        float* scT = (float*)((char*)d_ws + off_sc);
        prep_fused<<<PREP_GRID, 256, 0, stream>>>(x, wq, scales, s, Aq, sxw, Bq, scT);
        awq_gemm_i8<<<1408, THREADS, 0, stream>>>(Aq, Bq, scT, sxw, bias, out);
    } else {
        awq_gemm_fb<<<(TOKENS / 128) * (OUT_DIM / 128), 256, 0, stream>>>(x, wq, scales, s, bias, out);
    }
}